// Round 15
// baseline (446.009 us; speedup 1.0000x reference)
//
#include <hip/hip_runtime.h>

#define NN 50000
#define EE 800000
#define PGB ((NN + 31) / 32)      // 1563 pgemm blocks

typedef unsigned short u16;
typedef unsigned int u32;
typedef __attribute__((ext_vector_type(8))) short short8;
typedef __attribute__((ext_vector_type(4))) float f32x4;
typedef __attribute__((ext_vector_type(2))) float f32x2;

__device__ __forceinline__ u16 f2bf(float f) {
    union { float f; u32 i; } v; v.f = f;
    u32 x = v.i;
    return (u16)((x + 0x7fffu + ((x >> 16) & 1u)) >> 16);  // RNE (prep only)
}
// pack two f32 -> bf16 pair (round-half-up): 2 add + 1 v_perm
__device__ __forceinline__ u32 pkr(float lo, float hi) {
    union { float f; u32 i; } a, b; a.f = lo; b.f = hi;
    return __builtin_amdgcn_perm(b.i + 0x8000u, a.i + 0x8000u, 0x07060302u);
}
__device__ __forceinline__ float bf2f(short x) {
    union { u32 i; float f; } v; v.i = ((u32)(u16)x) << 16; return v.f;
}
// silu via hw rcp: avoids IEEE div sequence
__device__ __forceinline__ float siluf(float x) {
    return x * __builtin_amdgcn_rcpf(1.0f + __expf(-x));
}
__device__ __forceinline__ void atomic_pk_add_bf16(u16* addr, u32 data) {
    asm volatile("global_atomic_pk_add_bf16 %0, %1, off" :: "v"(addr), "v"(data) : "memory");
}

// B layout, column-interleaved tiles: group=n>>5, parity=n&1, slot=(n>>1)&15
__device__ __forceinline__ int b_idx2(int k, int n) {
    int chunk = ((k >> 5) << 3) + ((n >> 5) << 1) + (n & 1);
    return chunk * 512 + (((k >> 3) & 3) << 7) + (((n >> 1) & 15) << 3) + (k & 7);
}

// ---- fused prep (blocks 0..511) + hist w/ rank capture (blocks 512+) ----
__global__ __launch_bounds__(256) void prephist_kernel(
    const float* __restrict__ We1, const float* __restrict__ We2,
    const float* __restrict__ Wc1, const float* __restrict__ Wn1,
    const float* __restrict__ Wn2, const float* __restrict__ Wv1,
    u16* __restrict__ We1bf, u16* __restrict__ We2bf, u16* __restrict__ Wc1bf,
    u16* __restrict__ Wn1bf, u16* __restrict__ Wn2bf, u16* __restrict__ Wv1bf,
    const int* __restrict__ row, u32* __restrict__ bins,
    u32* __restrict__ rank, u32 use_ext)
{
    if (blockIdx.x >= 512) {
        int e = (blockIdx.x - 512) * 256 + threadIdx.x;
        if (e < EE) {
            u32 rk = atomicAdd(&bins[row[e]], 1u);
            if (use_ext) rank[e] = rk;
        }
        return;
    }
    int i = blockIdx.x * 256 + threadIdx.x;     // 0..131071
    if (i < 32768) {
        int k = i >> 7, n = i & 127;
        We1bf[b_idx2(k, n)] = f2bf(We1[k * 128 + n]);   // rows 0..255
    } else if (i < 49152) {
        int t = i - 32768; int k = t >> 7, n = t & 127;
        We2bf[b_idx2(k, n)] = f2bf(We2[k * 128 + n]);
    } else if (i < 65536) {
        int t = i - 49152; int k = t >> 7, n = t & 127;
        Wc1bf[b_idx2(k, n)] = f2bf(Wc1[k * 128 + n]);
    } else if (i < 98304) {
        int t = i - 65536; int k = t >> 7, n = t & 127;
        Wn1bf[b_idx2(k, n)] = f2bf(Wn1[k * 128 + n]);   // rows 0..255
    } else if (i < 114688) {
        int t = i - 98304; int k = t >> 7, n = t & 127;
        Wn2bf[b_idx2(k, n)] = f2bf(Wn2[k * 128 + n]);
    } else {
        int t = i - 114688; int k = t >> 7, n = t & 127;
        Wv1bf[b_idx2(k, n)] = f2bf(Wv1[k * 128 + n]);
    }
}

__global__ __launch_bounds__(256) void scan1_kernel(const u32* __restrict__ bins,
                                                    u32* __restrict__ part)
{
    __shared__ u32 wsum[4];
    int i = blockIdx.x * 256 + threadIdx.x;
    u32 v = (i < NN) ? bins[i] : 0u;
    #pragma unroll
    for (int o = 1; o < 64; o <<= 1) v += __shfl_xor(v, o);
    if ((threadIdx.x & 63) == 0) wsum[threadIdx.x >> 6] = v;
    __syncthreads();
    if (threadIdx.x == 0) part[blockIdx.x] = wsum[0] + wsum[1] + wsum[2] + wsum[3];
}

// scan3 with scan2 folded in: every block redundantly scans the 196 partials
__global__ __launch_bounds__(256) void scan3_kernel(const u32* __restrict__ bins,
                                                    const u32* __restrict__ part,
                                                    u32* __restrict__ cursor, int np)
{
    __shared__ u32 sPart[256];
    __shared__ u32 wsum[4];
    int t = threadIdx.x;
    sPart[t] = (t < np) ? part[t] : 0u;
    __syncthreads();
    if (t == 0) {
        u32 run = 0;
        for (int i = 0; i < np; ++i) { u32 x = sPart[i]; sPart[i] = run; run += x; }
    }
    int i = blockIdx.x * 256 + t;
    u32 v = (i < NN) ? bins[i] : 0u;
    u32 x = v;
    #pragma unroll
    for (int o = 1; o < 64; o <<= 1) {
        u32 y = __shfl_up(x, o);
        if ((t & 63) >= o) x += y;
    }
    if ((t & 63) == 63) wsum[t >> 6] = x;
    __syncthreads();
    u32 base = sPart[blockIdx.x];
    for (int wv = 0; wv < (t >> 6); ++wv) base += wsum[wv];
    if (i < NN) cursor[i] = base + x - v;   // exclusive prefix
}

// ---- fused: pgemm (blocks 0..PGB-1) | scatter (blocks PGB..) ----
__global__ __launch_bounds__(256, 4) void pgemm_scatter_kernel(
    const float* __restrict__ h, const float* __restrict__ be1,
    const float* __restrict__ bv1, const float* __restrict__ Wv2,
    const float* __restrict__ bv2,
    const u16* __restrict__ We1bf, const u16* __restrict__ Wv1bf,
    u16* __restrict__ P1bf, u16* __restrict__ P2bf,
    u16* __restrict__ hbf, u32 use_ext, float* __restrict__ vel,
    const int* __restrict__ row, const int* __restrict__ col,
    const float* __restrict__ cdiff, u32* __restrict__ cursor,
    const u32* __restrict__ rank, u32* __restrict__ edata)
{
    __shared__ u16 sX[4096];   // 8KB: 32 nodes x 128 k, slot = r + 32*kg
    __shared__ float sVelP[4][32];

    if (blockIdx.x >= PGB) {
        // ---- scatter branch: sorted edata {row, col, rad_bits, orig_e} ----
        int e = (blockIdx.x - PGB) * 256 + threadIdx.x;
        if (e < EE) {
            int r = row[e];
            u32 p = use_ext ? (cursor[r] + rank[e]) : atomicAdd(&cursor[r], 1u);
            float cx = cdiff[(size_t)e * 3 + 0];
            float cy = cdiff[(size_t)e * 3 + 1];
            float cz = cdiff[(size_t)e * 3 + 2];
            float rad = cx * cx + cy * cy + cz * cz;
            uint4 ed;
            ed.x = (u32)r;
            ed.y = (u32)col[e];
            ed.z = __float_as_uint(rad);
            ed.w = (u32)e;
            *(uint4*)(edata + (size_t)p * 4) = ed;
        }
        return;
    }

    const int tid = threadIdx.x;
    const int nblk = blockIdx.x * 32;
    const int w = tid >> 6;
    const int lane = tid & 63;
    const int m15 = lane & 15, q = lane >> 4;
    const int n0 = w * 32 + 2 * m15, n1 = n0 + 1;
    const int ard = (m15 + 32 * q) * 8;
    const float b0 = be1[n0], b1 = be1[n1];

    {
        int r = tid & 31, j = tid >> 5;          // j = 0..7
        int n = nblk + r; if (n > NN - 1) n = NN - 1;
        #pragma unroll
        for (int i = 0; i < 2; ++i) {
            int kg = j * 2 + i;                  // 0..15
            const float* src = h + (size_t)n * 128 + kg * 8;
            float4 a = *(const float4*)(src);
            float4 b = *(const float4*)(src + 4);
            uint4 v = make_uint4(pkr(a.x, a.y), pkr(a.z, a.w),
                                 pkr(b.x, b.y), pkr(b.z, b.w));
            *(uint4*)&sX[(r + 32 * kg) * 8] = v;
            if (use_ext)
                *(uint4*)(hbf + (size_t)n * 128 + kg * 8) = v;
        }
    }
    __syncthreads();

    f32x4 acc[2][2];

    // P1: We1 k-rows 0..127 (chunks c=0..3), bias be1 folded
    #pragma unroll
    for (int mt = 0; mt < 2; ++mt)
        #pragma unroll
        for (int r = 0; r < 4; ++r) { acc[mt][0][r] = b0; acc[mt][1][r] = b1; }
    #pragma unroll
    for (int c = 0; c < 4; ++c) {
        short8 bf0 = *(const short8*)(We1bf + (c * 8 + w * 2 + 0) * 512 + lane * 8);
        short8 bf1 = *(const short8*)(We1bf + (c * 8 + w * 2 + 1) * 512 + lane * 8);
        #pragma unroll
        for (int mt = 0; mt < 2; ++mt) {
            short8 af = *(const short8*)(sX + ard + c * 1024 + mt * 128);
            acc[mt][0] = __builtin_amdgcn_mfma_f32_16x16x32_bf16(af, bf0, acc[mt][0], 0, 0, 0);
            acc[mt][1] = __builtin_amdgcn_mfma_f32_16x16x32_bf16(af, bf1, acc[mt][1], 0, 0, 0);
        }
    }
    #pragma unroll
    for (int mt = 0; mt < 2; ++mt)
        #pragma unroll
        for (int r = 0; r < 4; ++r) {
            int n = nblk + mt * 16 + q * 4 + r;
            if (n < NN)
                *(u32*)(P1bf + (size_t)n * 128 + n0) = pkr(acc[mt][0][r], acc[mt][1][r]);
        }

    // P2: We1 k-rows 128..255 (chunks c=4..7), no bias; same A tile
    #pragma unroll
    for (int mt = 0; mt < 2; ++mt)
        #pragma unroll
        for (int r = 0; r < 4; ++r) { acc[mt][0][r] = 0.0f; acc[mt][1][r] = 0.0f; }
    #pragma unroll
    for (int c = 4; c < 8; ++c) {
        short8 bf0 = *(const short8*)(We1bf + (c * 8 + w * 2 + 0) * 512 + lane * 8);
        short8 bf1 = *(const short8*)(We1bf + (c * 8 + w * 2 + 1) * 512 + lane * 8);
        #pragma unroll
        for (int mt = 0; mt < 2; ++mt) {
            short8 af = *(const short8*)(sX + ard + (c - 4) * 1024 + mt * 128);
            acc[mt][0] = __builtin_amdgcn_mfma_f32_16x16x32_bf16(af, bf0, acc[mt][0], 0, 0, 0);
            acc[mt][1] = __builtin_amdgcn_mfma_f32_16x16x32_bf16(af, bf1, acc[mt][1], 0, 0, 0);
        }
    }
    #pragma unroll
    for (int mt = 0; mt < 2; ++mt)
        #pragma unroll
        for (int r = 0; r < 4; ++r) {
            int n = nblk + mt * 16 + q * 4 + r;
            if (n < NN)
                *(u32*)(P2bf + (size_t)n * 128 + n0) = pkr(acc[mt][0][r], acc[mt][1][r]);
        }

    // ---- vel head: vel = silu(h@Wv1+bv1)@Wv2 + bv2 (reuses staged h) ----
    {
        const float bva = bv1[n0], bvb = bv1[n1];
        const float wv2a = Wv2[n0], wv2b = Wv2[n1];
        #pragma unroll
        for (int mt = 0; mt < 2; ++mt)
            #pragma unroll
            for (int r = 0; r < 4; ++r) { acc[mt][0][r] = bva; acc[mt][1][r] = bvb; }
        #pragma unroll
        for (int c = 0; c < 4; ++c) {
            short8 bf0 = *(const short8*)(Wv1bf + (c * 8 + w * 2 + 0) * 512 + lane * 8);
            short8 bf1 = *(const short8*)(Wv1bf + (c * 8 + w * 2 + 1) * 512 + lane * 8);
            #pragma unroll
            for (int mt = 0; mt < 2; ++mt) {
                short8 af = *(const short8*)(sX + ard + c * 1024 + mt * 128);
                acc[mt][0] = __builtin_amdgcn_mfma_f32_16x16x32_bf16(af, bf0, acc[mt][0], 0, 0, 0);
                acc[mt][1] = __builtin_amdgcn_mfma_f32_16x16x32_bf16(af, bf1, acc[mt][1], 0, 0, 0);
            }
        }
        #pragma unroll
        for (int mt = 0; mt < 2; ++mt)
            #pragma unroll
            for (int r = 0; r < 4; ++r) {
                float pv = fmaf(siluf(acc[mt][0][r]), wv2a, siluf(acc[mt][1][r]) * wv2b);
                pv += __shfl_xor(pv, 1);
                pv += __shfl_xor(pv, 2);
                pv += __shfl_xor(pv, 4);
                pv += __shfl_xor(pv, 8);
                if (m15 == 0) sVelP[w][mt * 16 + q * 4 + r] = pv;
            }
        __syncthreads();
        if (tid < 32) {
            int n = nblk + tid;
            if (n < NN)
                vel[n] = bv2[0] + sVelP[0][tid] + sVelP[1][tid] + sVelP[2][tid] + sVelP[3][tid];
        }
    }
}

// ---- edge kernel: 64 edges/block, run-agg fused into GEMM2 epilogue ----
// XCD-aware bijective block swizzle: consecutive sorted-edge blocks land on
// the same XCD (shared P1 panels -> better per-XCD L2 hit).
__global__ __launch_bounds__(256, 8) void edge_kernel(
    const u16* __restrict__ P1bf, const u16* __restrict__ P2bf,
    const float* __restrict__ cdiff,
    const u32* __restrict__ edata,
    const float* __restrict__ We1,      // only row 256 (radial weights) used
    const float* __restrict__ be2, const float* __restrict__ bc1,
    const float* __restrict__ Wc2,
    const u16* __restrict__ We2bf, const u16* __restrict__ Wc1bf,
    u16* __restrict__ aggbf, float* __restrict__ fsum)
{
    __shared__ u16 sT[8192];        // 16KB swizzled A-fragment buffer (t1, then m)
    __shared__ int sRow[64];
    __shared__ int sEg[64];
    __shared__ int sRid[64];        // run-head index per edge (sorted rows)
    __shared__ float sCoefP[4][64];
    __shared__ float sF[192];       // per-run force accumulators [rid*3+ax]

    const int tid = threadIdx.x;
    // bijective XCD swizzle (nwg = EE/64 = 12500, 8 XCDs)
    const int xcd = blockIdx.x & 7, off = blockIdx.x >> 3;
    const int qq = 12500 >> 3, rr = 12500 & 7;      // 1562, 4
    const int lb = (xcd < rr ? xcd * (qq + 1) : rr * (qq + 1) + (xcd - rr) * qq) + off;
    const int e0 = lb * 64;
    const int w = tid >> 6;
    const int lane = tid & 63;
    const int m15 = lane & 15, q = lane >> 4;
    const int n0 = w * 32 + 2 * m15, n1 = n0 + 1;
    const int lsw = (lane ^ q) * 8;
    const int a_ = m15 >> 2;
    const int sbase = (a_ << 7) + (q << 5) + ((m15 & 3) << 1);
    const int o0 = (0 ^ a_) << 3, o1 = (1 ^ a_) << 3, o2 = (2 ^ a_) << 3, o3 = (3 ^ a_) << 3;

    const float b2a = be2[n0], b2b = be2[n1];
    const float b3a = bc1[n0], b3b = bc1[n1];
    const float wc2a = Wc2[n0], wc2b = Wc2[n1];

    // t1 = silu(P1[row] + P2[col] + rad*We1[256]) -> swizzled sT
    {
        int e = tid & 63, seg = tid >> 6;
        uint4 ed = *(const uint4*)(edata + (size_t)(e0 + e) * 4);
        int nr = (int)ed.x, nc = (int)ed.y;
        float rad = __uint_as_float(ed.z);
        if (seg == 0) { sRow[e] = nr; sEg[e] = (int)ed.w; }
        const u16* p1 = P1bf + (size_t)nr * 128 + seg * 32;
        const u16* p2 = P2bf + (size_t)nc * 128 + seg * 32;
        const float* wr = We1 + 256 * 128 + seg * 32;
        u16* tb = sT + (((seg * 4 + (e >> 4)) << 9) + (((e >> 2) & 3) << 5));
        const int rl = e & 3;
        #pragma unroll 2
        for (int g = 0; g < 4; ++g) {
            short8 x1 = *(const short8*)(p1 + g * 8);
            short8 x2 = *(const short8*)(p2 + g * 8);
            float4 wa = *(const float4*)(wr + g * 8);
            float4 wb = *(const float4*)(wr + g * 8 + 4);
            float v[8];
            #pragma unroll
            for (int t = 0; t < 4; ++t) {
                v[t]     = siluf(bf2f(x1[t])     + bf2f(x2[t])     + rad * ((const float*)&wa)[t]);
                v[t + 4] = siluf(bf2f(x1[t + 4]) + bf2f(x2[t + 4]) + rad * ((const float*)&wb)[t]);
            }
            uint4 dd = make_uint4(pkr(v[0], v[1]), pkr(v[2], v[3]),
                                  pkr(v[4], v[5]), pkr(v[6], v[7]));
            *(uint4*)(tb + ((g << 7) + ((rl ^ g) << 3))) = dd;
        }
    }
    __syncthreads();   // B1: t1 + sRow ready

    // run-head ids via 6-step max-scan (wave 0); zero force accumulators
    if (tid < 64) {
        int e = tid;
        int head = (e == 0) || (sRow[e] != sRow[e - 1]);
        int v = head ? e : 0;
        #pragma unroll
        for (int o = 1; o < 64; o <<= 1) {
            int y = __shfl_up(v, o);
            if (e >= o && y > v) v = y;
        }
        sRid[e] = v;
        sF[e * 3 + 0] = 0.f; sF[e * 3 + 1] = 0.f; sF[e * 3 + 2] = 0.f;
    }

    f32x4 acc[4][2];
    u32 d[4][4];

    // ---- GEMM2: m = silu(t1 @ We2 + be2), K=128 ----
    #pragma unroll
    for (int mt = 0; mt < 4; ++mt)
        #pragma unroll
        for (int r = 0; r < 4; ++r) { acc[mt][0][r] = b2a; acc[mt][1][r] = b2b; }
    #pragma unroll
    for (int c = 0; c < 4; ++c) {
        short8 bf0 = *(const short8*)(We2bf + (c * 8 + w * 2 + 0) * 512 + lane * 8);
        short8 bf1 = *(const short8*)(We2bf + (c * 8 + w * 2 + 1) * 512 + lane * 8);
        #pragma unroll
        for (int mt = 0; mt < 4; ++mt) {
            short8 af = *(const short8*)(sT + (c * 4 + mt) * 512 + lsw);
            acc[mt][0] = __builtin_amdgcn_mfma_f32_16x16x32_bf16(af, bf0, acc[mt][0], 0, 0, 0);
            acc[mt][1] = __builtin_amdgcn_mfma_f32_16x16x32_bf16(af, bf1, acc[mt][1], 0, 0, 0);
        }
    }
    // epilogue: silu + pack; run-aggregate f32 sums per 4-edge chunk and
    // issue agg atomics NOW (pre-B2; edges mt*16+q*4+r are r-contiguous)
    #pragma unroll
    for (int mt = 0; mt < 4; ++mt) {
        float s0 = 0.f, s1 = 0.f;
        int prow = sRow[mt * 16 + q * 4];
        #pragma unroll
        for (int r = 0; r < 4; ++r) {
            int rr2 = sRow[mt * 16 + q * 4 + r];
            float sl0 = siluf(acc[mt][0][r]);
            float sl1 = siluf(acc[mt][1][r]);
            d[mt][r] = pkr(sl0, sl1);
            if (rr2 != prow) {
                atomic_pk_add_bf16(aggbf + (size_t)prow * 128 + n0, pkr(s0, s1));
                s0 = 0.f; s1 = 0.f; prow = rr2;
            }
            s0 += sl0; s1 += sl1;
        }
        atomic_pk_add_bf16(aggbf + (size_t)prow * 128 + n0, pkr(s0, s1));
    }
    __syncthreads();   // B2: all sT reads done -> reuse for m
    #pragma unroll
    for (int mt = 0; mt < 4; ++mt) {
        u16* bp = sT + (w * 4 + mt) * 512 + sbase;
        *(u32*)(bp + o0) = d[mt][0];
        *(u32*)(bp + o1) = d[mt][1];
        *(u32*)(bp + o2) = d[mt][2];
        *(u32*)(bp + o3) = d[mt][3];
    }
    __syncthreads();   // B3: m ready

    // ---- GEMM3: u = silu(m @ Wc1 + bc1); coef fused via shfl reduce ----
    #pragma unroll
    for (int mt = 0; mt < 4; ++mt)
        #pragma unroll
        for (int r = 0; r < 4; ++r) { acc[mt][0][r] = b3a; acc[mt][1][r] = b3b; }
    #pragma unroll
    for (int c = 0; c < 4; ++c) {
        short8 bf0 = *(const short8*)(Wc1bf + (c * 8 + w * 2 + 0) * 512 + lane * 8);
        short8 bf1 = *(const short8*)(Wc1bf + (c * 8 + w * 2 + 1) * 512 + lane * 8);
        #pragma unroll
        for (int mt = 0; mt < 4; ++mt) {
            short8 af = *(const short8*)(sT + (c * 4 + mt) * 512 + lsw);
            acc[mt][0] = __builtin_amdgcn_mfma_f32_16x16x32_bf16(af, bf0, acc[mt][0], 0, 0, 0);
            acc[mt][1] = __builtin_amdgcn_mfma_f32_16x16x32_bf16(af, bf1, acc[mt][1], 0, 0, 0);
        }
    }
    #pragma unroll
    for (int mt = 0; mt < 4; ++mt)
        #pragma unroll
        for (int r = 0; r < 4; ++r) {
            float pv = fmaf(siluf(acc[mt][0][r]), wc2a, siluf(acc[mt][1][r]) * wc2b);
            pv += __shfl_xor(pv, 1);
            pv += __shfl_xor(pv, 2);
            pv += __shfl_xor(pv, 4);
            pv += __shfl_xor(pv, 8);
            if (m15 == 0) sCoefP[w][mt * 16 + q * 4 + r] = pv;
        }
    __syncthreads();   // B4: coef partials + sRid + sF ready

    // force: per-edge clamped tr -> LDS run accumulators -> 1 atomic/(run,ax)
    if (tid < 192) {
        int e = tid / 3, ax = tid - e * 3;
        float coef = sCoefP[0][e] + sCoefP[1][e] + sCoefP[2][e] + sCoefP[3][e];
        float tr = cdiff[(size_t)sEg[e] * 3 + ax] * coef;
        tr = fminf(fmaxf(tr, -100.f), 100.f);
        atomicAdd(&sF[sRid[e] * 3 + ax], tr);
    }
    __syncthreads();   // B5: LDS force sums complete
    if (tid < 192) {
        int e = tid / 3, ax = tid - e * 3;
        if (e == 0 || sRow[e] != sRow[e - 1])
            atomicAdd(&fsum[(size_t)sRow[e] * 3 + ax], sF[e * 3 + ax]);
    }
}

// ---- node kernel: 32 nodes/block (1563 blocks), 4 waves; no vel head ----
__global__ __launch_bounds__(256, 4) void node_kernel(
    const float* __restrict__ h, const u16* __restrict__ hbf, u32 use_ext,
    const float* __restrict__ bn1, const float* __restrict__ bn2,
    const u16* __restrict__ Wn1bf, const u16* __restrict__ Wn2bf,
    const u16* __restrict__ aggbf, const float* __restrict__ fsum,
    const u32* __restrict__ bins, float* __restrict__ out)
{
    __shared__ u16 sX[8192];           // 16KB: 32 nodes x 256 k, slot = r + 32*kg
    __shared__ float sBn1[128], sBn2[128];
    u16* sT = sX + 4096;               // aliases agg half (k=128..255) after GEMM1

    const int tid = threadIdx.x;
    const int nblk = blockIdx.x * 32;
    const int w = tid >> 6;
    const int lane = tid & 63;
    const int m15 = lane & 15, q = lane >> 4;
    const int n0 = w * 32 + 2 * m15, n1 = n0 + 1;
    const int lsw = (lane ^ q) * 8;
    const int a_ = m15 >> 2;
    const int sbase = (a_ << 7) + (q << 5) + ((m15 & 3) << 1);
    const int o0 = (0 ^ a_) << 3, o1 = (1 ^ a_) << 3, o2 = (2 ^ a_) << 3, o3 = (3 ^ a_) << 3;
    const int ard = (m15 + 32 * q) * 8;

    if (tid < 96) {
        int r = tid / 3, ax = tid - r * 3;
        int n = nblk + r;
        if (n < NN)
            out[NN + (size_t)n * 3 + ax] = fsum[(size_t)n * 3 + ax] * __builtin_amdgcn_rcpf(fmaxf((float)bins[n], 1.0f));
    }
    if (tid < 128) { sBn1[tid] = bn1[tid]; sBn2[tid] = bn2[tid]; }

    {
        int r = tid & 31, j = tid >> 5;            // j = 0..7
        int n = nblk + r; if (n > NN - 1) n = NN - 1;
        if (j < 4) {
            if (use_ext) {
                #pragma unroll
                for (int i = 0; i < 4; ++i) {
                    int kg = j * 4 + i;            // 0..15  (h, k=0..127)
                    *(uint4*)&sX[(r + 32 * kg) * 8] =
                        *(const uint4*)(hbf + (size_t)n * 128 + kg * 8);
                }
            } else {
                #pragma unroll
                for (int i = 0; i < 4; ++i) {
                    int kg = j * 4 + i;
                    const float* src = h + (size_t)n * 128 + kg * 8;
                    float4 a = *(const float4*)(src);
                    float4 b = *(const float4*)(src + 4);
                    *(uint4*)&sX[(r + 32 * kg) * 8] = make_uint4(pkr(a.x, a.y), pkr(a.z, a.w),
                                                                 pkr(b.x, b.y), pkr(b.z, b.w));
                }
            }
        } else {
            #pragma unroll
            for (int i = 0; i < 4; ++i) {
                int kg = j * 4 + i;                // 16..31 (agg, k=128..255)
                *(uint4*)&sX[(r + 32 * kg) * 8] =
                    *(const uint4*)(aggbf + (size_t)n * 128 + (kg - 16) * 8);
            }
        }
    }
    __syncthreads();

    f32x4 acc[2][2];

    {
        float b0 = sBn1[n0], b1 = sBn1[n1];
        #pragma unroll
        for (int mt = 0; mt < 2; ++mt)
            #pragma unroll
            for (int r = 0; r < 4; ++r) { acc[mt][0][r] = b0; acc[mt][1][r] = b1; }
    }
    #pragma unroll
    for (int c = 0; c < 8; ++c) {
        short8 bf0 = *(const short8*)(Wn1bf + (c * 8 + w * 2 + 0) * 512 + lane * 8);
        short8 bf1 = *(const short8*)(Wn1bf + (c * 8 + w * 2 + 1) * 512 + lane * 8);
        #pragma unroll
        for (int mt = 0; mt < 2; ++mt) {
            short8 af = *(const short8*)(sX + ard + c * 1024 + mt * 128);
            acc[mt][0] = __builtin_amdgcn_mfma_f32_16x16x32_bf16(af, bf0, acc[mt][0], 0, 0, 0);
            acc[mt][1] = __builtin_amdgcn_mfma_f32_16x16x32_bf16(af, bf1, acc[mt][1], 0, 0, 0);
        }
    }
    u32 dn[2][4];
    #pragma unroll
    for (int mt = 0; mt < 2; ++mt)
        #pragma unroll
        for (int r = 0; r < 4; ++r)
            dn[mt][r] = pkr(siluf(acc[mt][0][r]), siluf(acc[mt][1][r]));
    __syncthreads();
    #pragma unroll
    for (int mt = 0; mt < 2; ++mt) {
        u16* bp = sT + (w * 2 + mt) * 512 + sbase;
        *(u32*)(bp + o0) = dn[mt][0];
        *(u32*)(bp + o1) = dn[mt][1];
        *(u32*)(bp + o2) = dn[mt][2];
        *(u32*)(bp + o3) = dn[mt][3];
    }
    __syncthreads();

    {
        float b0 = sBn2[n0], b1 = sBn2[n1];
        #pragma unroll
        for (int mt = 0; mt < 2; ++mt)
            #pragma unroll
            for (int r = 0; r < 4; ++r) { acc[mt][0][r] = b0; acc[mt][1][r] = b1; }
    }
    #pragma unroll
    for (int c = 0; c < 4; ++c) {
        short8 bf0 = *(const short8*)(Wn2bf + (c * 8 + w * 2 + 0) * 512 + lane * 8);
        short8 bf1 = *(const short8*)(Wn2bf + (c * 8 + w * 2 + 1) * 512 + lane * 8);
        #pragma unroll
        for (int mt = 0; mt < 2; ++mt) {
            short8 af = *(const short8*)(sT + (c * 2 + mt) * 512 + lsw);
            acc[mt][0] = __builtin_amdgcn_mfma_f32_16x16x32_bf16(af, bf0, acc[mt][0], 0, 0, 0);
            acc[mt][1] = __builtin_amdgcn_mfma_f32_16x16x32_bf16(af, bf1, acc[mt][1], 0, 0, 0);
        }
    }
    #pragma unroll
    for (int mt = 0; mt < 2; ++mt)
        #pragma unroll
        for (int r = 0; r < 4; ++r) {
            int n = nblk + mt * 16 + q * 4 + r;
            if (n < NN) {
                f32x2 v; v.x = acc[mt][0][r]; v.y = acc[mt][1][r];
                *(f32x2*)(out + (size_t)4 * NN + (size_t)n * 128 + n0) = v;
            }
        }
}

extern "C" void kernel_launch(void* const* d_in, const int* in_sizes, int n_in,
                              void* d_out, int out_size, void* d_ws, size_t ws_size,
                              hipStream_t stream) {
    const float* h     = (const float*)d_in[0];
    const float* cdiff = (const float*)d_in[1];
    const int* row     = (const int*)d_in[2];
    const int* col     = (const int*)d_in[3];
    const float* We1 = (const float*)d_in[4];
    const float* be1 = (const float*)d_in[5];
    const float* We2 = (const float*)d_in[6];
    const float* be2 = (const float*)d_in[7];
    const float* Wn1 = (const float*)d_in[8];
    const float* bn1 = (const float*)d_in[9];
    const float* Wn2 = (const float*)d_in[10];
    const float* bn2 = (const float*)d_in[11];
    const float* Wc1 = (const float*)d_in[12];
    const float* bc1 = (const float*)d_in[13];
    const float* Wc2 = (const float*)d_in[14];
    const float* Wv1 = (const float*)d_in[15];
    const float* bv1 = (const float*)d_in[16];
    const float* Wv2 = (const float*)d_in[17];
    const float* bv2 = (const float*)d_in[18];

    // base workspace (~26.7MB, verified layout):
    u16* aggbf  = (u16*)d_ws;                           // [NN*128] bf16
    float* fsum = (float*)(aggbf + (size_t)NN * 128);   // [NN*3]
    u32* bins   = (u32*)(fsum + (size_t)NN * 3);        // [NN]
    u16* We1bf = (u16*)(bins + NN);                     // [32768]
    u16* We2bf = We1bf + 32768;                         // [16384]
    u16* Wc1bf = We2bf + 16384;                         // [16384]
    u16* Wn1bf = Wc1bf + 16384;                         // [32768]
    u16* Wn2bf = Wn1bf + 32768;                         // [16384]
    u16* Wv1bf = Wn2bf + 16384;                         // [16384]
    u16* P1bf  = Wv1bf + 16384;                         // [NN*128] bf16
    float* out = (float*)d_out;

    // ws extensions: hbf + rank (39.7MB total; guarded)
    const size_t base_bytes = (size_t)26662144;
    u16* hbf  = (u16*)((char*)d_ws + base_bytes);                     // [NN*128]
    u32* rank = (u32*)((char*)d_ws + base_bytes + (size_t)NN * 256);  // [EE]
    u32 use_ext = (ws_size >= base_bytes + (size_t)NN * 256 + (size_t)EE * 4) ? 1u : 0u;

    // d_out: vel [0,NN) written by pgemm; force region [NN,4NN) hosts sort
    // scratch (cursor+part, 201KB of 600KB) until node overwrites it last.
    u32* cursor = (u32*)(out + NN);                     // [NN]
    u32* part   = cursor + NN;                          // [196]
    // h_out region (25.6MB): P2 (12.8) + edata (12.8) — consumed by edge
    u16* P2bf   = (u16*)(out + (size_t)4 * NN);         // [NN*128]
    u32* edata  = (u32*)(P2bf + (size_t)NN * 128);      // [EE*4] uint4/edge

    size_t zero_bytes = (size_t)NN * 128 * 2 + (size_t)NN * 3 * 4 + (size_t)NN * 4;
    hipMemsetAsync(d_ws, 0, zero_bytes, stream);        // aggbf + fsum + bins

    const int NSC = (NN + 255) / 256;                   // 196 scan blocks

    prephist_kernel<<<512 + (EE + 255) / 256, 256, 0, stream>>>(
        We1, We2, Wc1, Wn1, Wn2, Wv1,
        We1bf, We2bf, Wc1bf, Wn1bf, Wn2bf, Wv1bf,
        row, bins, rank, use_ext);
    scan1_kernel<<<NSC, 256, 0, stream>>>(bins, part);
    scan3_kernel<<<NSC, 256, 0, stream>>>(bins, part, cursor, NSC);
    pgemm_scatter_kernel<<<PGB + (EE + 255) / 256, 256, 0, stream>>>(
        h, be1, bv1, Wv2, bv2,
        We1bf, Wv1bf, P1bf, P2bf,
        hbf, use_ext, out,
        row, col, cdiff, cursor, rank, edata);
    edge_kernel<<<EE / 64, 256, 0, stream>>>(P1bf, P2bf, cdiff, edata,
                                             We1, be2, bc1, Wc2,
                                             We2bf, Wc1bf,
                                             aggbf, fsum);
    node_kernel<<<(NN + 31) / 32, 256, 0, stream>>>(h, hbf, use_ext,
                                                    bn1, bn2,
                                                    Wn1bf, Wn2bf,
                                                    aggbf, fsum, bins, out);
}

// Round 16
// 341.061 us; speedup vs baseline: 1.3077x; 1.3077x over previous
//
#include <hip/hip_runtime.h>

#define NN 50000
#define EE 800000
#define PGB ((NN + 31) / 32)      // 1563 pgemm blocks

typedef unsigned short u16;
typedef unsigned int u32;
typedef __attribute__((ext_vector_type(8))) short short8;
typedef __attribute__((ext_vector_type(4))) float f32x4;
typedef __attribute__((ext_vector_type(2))) float f32x2;

__device__ __forceinline__ u16 f2bf(float f) {
    union { float f; u32 i; } v; v.f = f;
    u32 x = v.i;
    return (u16)((x + 0x7fffu + ((x >> 16) & 1u)) >> 16);  // RNE (prep only)
}
// pack two f32 -> bf16 pair (round-half-up): 2 add + 1 v_perm
__device__ __forceinline__ u32 pkr(float lo, float hi) {
    union { float f; u32 i; } a, b; a.f = lo; b.f = hi;
    return __builtin_amdgcn_perm(b.i + 0x8000u, a.i + 0x8000u, 0x07060302u);
}
__device__ __forceinline__ float bf2f(short x) {
    union { u32 i; float f; } v; v.i = ((u32)(u16)x) << 16; return v.f;
}
// silu via hw rcp: avoids IEEE div sequence
__device__ __forceinline__ float siluf(float x) {
    return x * __builtin_amdgcn_rcpf(1.0f + __expf(-x));
}
__device__ __forceinline__ void atomic_pk_add_bf16(u16* addr, u32 data) {
    asm volatile("global_atomic_pk_add_bf16 %0, %1, off" :: "v"(addr), "v"(data) : "memory");
}

// B layout, column-interleaved tiles: group=n>>5, parity=n&1, slot=(n>>1)&15
__device__ __forceinline__ int b_idx2(int k, int n) {
    int chunk = ((k >> 5) << 3) + ((n >> 5) << 1) + (n & 1);
    return chunk * 512 + (((k >> 3) & 3) << 7) + (((n >> 1) & 15) << 3) + (k & 7);
}

// ---- fused prep (blocks 0..511) + hist w/ rank capture (blocks 512+) ----
__global__ __launch_bounds__(256) void prephist_kernel(
    const float* __restrict__ We1, const float* __restrict__ We2,
    const float* __restrict__ Wc1, const float* __restrict__ Wn1,
    const float* __restrict__ Wn2, const float* __restrict__ Wv1,
    u16* __restrict__ We1bf, u16* __restrict__ We2bf, u16* __restrict__ Wc1bf,
    u16* __restrict__ Wn1bf, u16* __restrict__ Wn2bf, u16* __restrict__ Wv1bf,
    const int* __restrict__ row, u32* __restrict__ bins,
    u32* __restrict__ rank, u32 use_ext)
{
    if (blockIdx.x >= 512) {
        int e = (blockIdx.x - 512) * 256 + threadIdx.x;
        if (e < EE) {
            u32 rk = atomicAdd(&bins[row[e]], 1u);
            if (use_ext) rank[e] = rk;
        }
        return;
    }
    int i = blockIdx.x * 256 + threadIdx.x;     // 0..131071
    if (i < 32768) {
        int k = i >> 7, n = i & 127;
        We1bf[b_idx2(k, n)] = f2bf(We1[k * 128 + n]);   // rows 0..255
    } else if (i < 49152) {
        int t = i - 32768; int k = t >> 7, n = t & 127;
        We2bf[b_idx2(k, n)] = f2bf(We2[k * 128 + n]);
    } else if (i < 65536) {
        int t = i - 49152; int k = t >> 7, n = t & 127;
        Wc1bf[b_idx2(k, n)] = f2bf(Wc1[k * 128 + n]);
    } else if (i < 98304) {
        int t = i - 65536; int k = t >> 7, n = t & 127;
        Wn1bf[b_idx2(k, n)] = f2bf(Wn1[k * 128 + n]);   // rows 0..255
    } else if (i < 114688) {
        int t = i - 98304; int k = t >> 7, n = t & 127;
        Wn2bf[b_idx2(k, n)] = f2bf(Wn2[k * 128 + n]);
    } else {
        int t = i - 114688; int k = t >> 7, n = t & 127;
        Wv1bf[b_idx2(k, n)] = f2bf(Wv1[k * 128 + n]);
    }
}

__global__ __launch_bounds__(256) void scan1_kernel(const u32* __restrict__ bins,
                                                    u32* __restrict__ part)
{
    __shared__ u32 wsum[4];
    int i = blockIdx.x * 256 + threadIdx.x;
    u32 v = (i < NN) ? bins[i] : 0u;
    #pragma unroll
    for (int o = 1; o < 64; o <<= 1) v += __shfl_xor(v, o);
    if ((threadIdx.x & 63) == 0) wsum[threadIdx.x >> 6] = v;
    __syncthreads();
    if (threadIdx.x == 0) part[blockIdx.x] = wsum[0] + wsum[1] + wsum[2] + wsum[3];
}

// scan3 with scan2 folded in: every block redundantly scans the 196 partials
__global__ __launch_bounds__(256) void scan3_kernel(const u32* __restrict__ bins,
                                                    const u32* __restrict__ part,
                                                    u32* __restrict__ cursor, int np)
{
    __shared__ u32 sPart[256];
    __shared__ u32 wsum[4];
    int t = threadIdx.x;
    sPart[t] = (t < np) ? part[t] : 0u;
    __syncthreads();
    if (t == 0) {
        u32 run = 0;
        for (int i = 0; i < np; ++i) { u32 x = sPart[i]; sPart[i] = run; run += x; }
    }
    int i = blockIdx.x * 256 + t;
    u32 v = (i < NN) ? bins[i] : 0u;
    u32 x = v;
    #pragma unroll
    for (int o = 1; o < 64; o <<= 1) {
        u32 y = __shfl_up(x, o);
        if ((t & 63) >= o) x += y;
    }
    if ((t & 63) == 63) wsum[t >> 6] = x;
    __syncthreads();
    u32 base = sPart[blockIdx.x];
    for (int wv = 0; wv < (t >> 6); ++wv) base += wsum[wv];
    if (i < NN) cursor[i] = base + x - v;   // exclusive prefix
}

// ---- fused: pgemm (blocks 0..PGB-1) | scatter (blocks PGB..) ----
__global__ __launch_bounds__(256, 4) void pgemm_scatter_kernel(
    const float* __restrict__ h, const float* __restrict__ be1,
    const float* __restrict__ bv1, const float* __restrict__ Wv2,
    const float* __restrict__ bv2,
    const u16* __restrict__ We1bf, const u16* __restrict__ Wv1bf,
    u16* __restrict__ P1bf, u16* __restrict__ P2bf,
    u16* __restrict__ hbf, u32 use_ext, float* __restrict__ vel,
    const int* __restrict__ row, const int* __restrict__ col,
    const float* __restrict__ cdiff, u32* __restrict__ cursor,
    const u32* __restrict__ rank, u32* __restrict__ edata)
{
    __shared__ u16 sX[4096];   // 8KB: 32 nodes x 128 k, slot = r + 32*kg
    __shared__ float sVelP[4][32];

    if (blockIdx.x >= PGB) {
        // ---- scatter branch: sorted edata {row, col, rad_bits, orig_e} ----
        int e = (blockIdx.x - PGB) * 256 + threadIdx.x;
        if (e < EE) {
            int r = row[e];
            u32 p = use_ext ? (cursor[r] + rank[e]) : atomicAdd(&cursor[r], 1u);
            float cx = cdiff[(size_t)e * 3 + 0];
            float cy = cdiff[(size_t)e * 3 + 1];
            float cz = cdiff[(size_t)e * 3 + 2];
            float rad = cx * cx + cy * cy + cz * cz;
            uint4 ed;
            ed.x = (u32)r;
            ed.y = (u32)col[e];
            ed.z = __float_as_uint(rad);
            ed.w = (u32)e;
            *(uint4*)(edata + (size_t)p * 4) = ed;
        }
        return;
    }

    const int tid = threadIdx.x;
    const int nblk = blockIdx.x * 32;
    const int w = tid >> 6;
    const int lane = tid & 63;
    const int m15 = lane & 15, q = lane >> 4;
    const int n0 = w * 32 + 2 * m15, n1 = n0 + 1;
    const int ard = (m15 + 32 * q) * 8;
    const float b0 = be1[n0], b1 = be1[n1];

    {
        int r = tid & 31, j = tid >> 5;          // j = 0..7
        int n = nblk + r; if (n > NN - 1) n = NN - 1;
        #pragma unroll
        for (int i = 0; i < 2; ++i) {
            int kg = j * 2 + i;                  // 0..15
            const float* src = h + (size_t)n * 128 + kg * 8;
            float4 a = *(const float4*)(src);
            float4 b = *(const float4*)(src + 4);
            uint4 v = make_uint4(pkr(a.x, a.y), pkr(a.z, a.w),
                                 pkr(b.x, b.y), pkr(b.z, b.w));
            *(uint4*)&sX[(r + 32 * kg) * 8] = v;
            if (use_ext)
                *(uint4*)(hbf + (size_t)n * 128 + kg * 8) = v;
        }
    }
    __syncthreads();

    f32x4 acc[2][2];

    // P1: We1 k-rows 0..127 (chunks c=0..3), bias be1 folded
    #pragma unroll
    for (int mt = 0; mt < 2; ++mt)
        #pragma unroll
        for (int r = 0; r < 4; ++r) { acc[mt][0][r] = b0; acc[mt][1][r] = b1; }
    #pragma unroll
    for (int c = 0; c < 4; ++c) {
        short8 bf0 = *(const short8*)(We1bf + (c * 8 + w * 2 + 0) * 512 + lane * 8);
        short8 bf1 = *(const short8*)(We1bf + (c * 8 + w * 2 + 1) * 512 + lane * 8);
        #pragma unroll
        for (int mt = 0; mt < 2; ++mt) {
            short8 af = *(const short8*)(sX + ard + c * 1024 + mt * 128);
            acc[mt][0] = __builtin_amdgcn_mfma_f32_16x16x32_bf16(af, bf0, acc[mt][0], 0, 0, 0);
            acc[mt][1] = __builtin_amdgcn_mfma_f32_16x16x32_bf16(af, bf1, acc[mt][1], 0, 0, 0);
        }
    }
    #pragma unroll
    for (int mt = 0; mt < 2; ++mt)
        #pragma unroll
        for (int r = 0; r < 4; ++r) {
            int n = nblk + mt * 16 + q * 4 + r;
            if (n < NN)
                *(u32*)(P1bf + (size_t)n * 128 + n0) = pkr(acc[mt][0][r], acc[mt][1][r]);
        }

    // P2: We1 k-rows 128..255 (chunks c=4..7), no bias; same A tile
    #pragma unroll
    for (int mt = 0; mt < 2; ++mt)
        #pragma unroll
        for (int r = 0; r < 4; ++r) { acc[mt][0][r] = 0.0f; acc[mt][1][r] = 0.0f; }
    #pragma unroll
    for (int c = 4; c < 8; ++c) {
        short8 bf0 = *(const short8*)(We1bf + (c * 8 + w * 2 + 0) * 512 + lane * 8);
        short8 bf1 = *(const short8*)(We1bf + (c * 8 + w * 2 + 1) * 512 + lane * 8);
        #pragma unroll
        for (int mt = 0; mt < 2; ++mt) {
            short8 af = *(const short8*)(sX + ard + (c - 4) * 1024 + mt * 128);
            acc[mt][0] = __builtin_amdgcn_mfma_f32_16x16x32_bf16(af, bf0, acc[mt][0], 0, 0, 0);
            acc[mt][1] = __builtin_amdgcn_mfma_f32_16x16x32_bf16(af, bf1, acc[mt][1], 0, 0, 0);
        }
    }
    #pragma unroll
    for (int mt = 0; mt < 2; ++mt)
        #pragma unroll
        for (int r = 0; r < 4; ++r) {
            int n = nblk + mt * 16 + q * 4 + r;
            if (n < NN)
                *(u32*)(P2bf + (size_t)n * 128 + n0) = pkr(acc[mt][0][r], acc[mt][1][r]);
        }

    // ---- vel head: vel = silu(h@Wv1+bv1)@Wv2 + bv2 (reuses staged h) ----
    {
        const float bva = bv1[n0], bvb = bv1[n1];
        const float wv2a = Wv2[n0], wv2b = Wv2[n1];
        #pragma unroll
        for (int mt = 0; mt < 2; ++mt)
            #pragma unroll
            for (int r = 0; r < 4; ++r) { acc[mt][0][r] = bva; acc[mt][1][r] = bvb; }
        #pragma unroll
        for (int c = 0; c < 4; ++c) {
            short8 bf0 = *(const short8*)(Wv1bf + (c * 8 + w * 2 + 0) * 512 + lane * 8);
            short8 bf1 = *(const short8*)(Wv1bf + (c * 8 + w * 2 + 1) * 512 + lane * 8);
            #pragma unroll
            for (int mt = 0; mt < 2; ++mt) {
                short8 af = *(const short8*)(sX + ard + c * 1024 + mt * 128);
                acc[mt][0] = __builtin_amdgcn_mfma_f32_16x16x32_bf16(af, bf0, acc[mt][0], 0, 0, 0);
                acc[mt][1] = __builtin_amdgcn_mfma_f32_16x16x32_bf16(af, bf1, acc[mt][1], 0, 0, 0);
            }
        }
        #pragma unroll
        for (int mt = 0; mt < 2; ++mt)
            #pragma unroll
            for (int r = 0; r < 4; ++r) {
                float pv = fmaf(siluf(acc[mt][0][r]), wv2a, siluf(acc[mt][1][r]) * wv2b);
                pv += __shfl_xor(pv, 1);
                pv += __shfl_xor(pv, 2);
                pv += __shfl_xor(pv, 4);
                pv += __shfl_xor(pv, 8);
                if (m15 == 0) sVelP[w][mt * 16 + q * 4 + r] = pv;
            }
        __syncthreads();
        if (tid < 32) {
            int n = nblk + tid;
            if (n < NN)
                vel[n] = bv2[0] + sVelP[0][tid] + sVelP[1][tid] + sVelP[2][tid] + sVelP[3][tid];
        }
    }
}

// ---- edge kernel: R13-proven body + XCD-aware bijective block swizzle ----
__global__ __launch_bounds__(256, 8) void edge_kernel(
    const u16* __restrict__ P1bf, const u16* __restrict__ P2bf,
    const float* __restrict__ cdiff,
    const u32* __restrict__ edata,
    const float* __restrict__ We1,      // only row 256 (radial weights) used
    const float* __restrict__ be2, const float* __restrict__ bc1,
    const float* __restrict__ Wc2,
    const u16* __restrict__ We2bf, const u16* __restrict__ Wc1bf,
    u16* __restrict__ aggbf, float* __restrict__ fsum)
{
    __shared__ u16 sT[8192];        // 16KB swizzled A-fragment buffer (t1, then m)
    __shared__ int sRow[64];
    __shared__ int sEg[64];
    __shared__ int sRid[64];        // run-head index per edge (sorted rows)
    __shared__ float sCoefP[4][64];
    __shared__ float sF[192];       // per-run force accumulators [rid*3+ax]

    const int tid = threadIdx.x;
    // bijective XCD swizzle (nwg = EE/64 = 12500, 8 XCDs)
    const int xcd = blockIdx.x & 7, off = blockIdx.x >> 3;
    const int qq = 12500 >> 3, rr = 12500 & 7;      // 1562, 4
    const int lb = (xcd < rr ? xcd * (qq + 1) : rr * (qq + 1) + (xcd - rr) * qq) + off;
    const int e0 = lb * 64;
    const int w = tid >> 6;
    const int lane = tid & 63;
    const int m15 = lane & 15, q = lane >> 4;
    const int n0 = w * 32 + 2 * m15, n1 = n0 + 1;
    const int lsw = (lane ^ q) * 8;
    const int a_ = m15 >> 2;
    const int sbase = (a_ << 7) + (q << 5) + ((m15 & 3) << 1);
    const int o0 = (0 ^ a_) << 3, o1 = (1 ^ a_) << 3, o2 = (2 ^ a_) << 3, o3 = (3 ^ a_) << 3;

    const float b2a = be2[n0], b2b = be2[n1];
    const float b3a = bc1[n0], b3b = bc1[n1];
    const float wc2a = Wc2[n0], wc2b = Wc2[n1];

    // t1 = silu(P1[row] + P2[col] + rad*We1[256]) -> swizzled sT
    {
        int e = tid & 63, seg = tid >> 6;
        uint4 ed = *(const uint4*)(edata + (size_t)(e0 + e) * 4);
        int nr = (int)ed.x, nc = (int)ed.y;
        float rad = __uint_as_float(ed.z);
        if (seg == 0) { sRow[e] = nr; sEg[e] = (int)ed.w; }
        const u16* p1 = P1bf + (size_t)nr * 128 + seg * 32;
        const u16* p2 = P2bf + (size_t)nc * 128 + seg * 32;
        const float* wr = We1 + 256 * 128 + seg * 32;
        u16* tb = sT + (((seg * 4 + (e >> 4)) << 9) + (((e >> 2) & 3) << 5));
        const int rl = e & 3;
        #pragma unroll 2
        for (int g = 0; g < 4; ++g) {
            short8 x1 = *(const short8*)(p1 + g * 8);
            short8 x2 = *(const short8*)(p2 + g * 8);
            float4 wa = *(const float4*)(wr + g * 8);
            float4 wb = *(const float4*)(wr + g * 8 + 4);
            float v[8];
            #pragma unroll
            for (int t = 0; t < 4; ++t) {
                v[t]     = siluf(bf2f(x1[t])     + bf2f(x2[t])     + rad * ((const float*)&wa)[t]);
                v[t + 4] = siluf(bf2f(x1[t + 4]) + bf2f(x2[t + 4]) + rad * ((const float*)&wb)[t]);
            }
            uint4 dd = make_uint4(pkr(v[0], v[1]), pkr(v[2], v[3]),
                                  pkr(v[4], v[5]), pkr(v[6], v[7]));
            *(uint4*)(tb + ((g << 7) + ((rl ^ g) << 3))) = dd;
        }
    }
    __syncthreads();   // B1: t1 + sRow ready

    // run-head ids via 6-step max-scan (wave 0); zero force accumulators
    if (tid < 64) {
        int e = tid;
        int head = (e == 0) || (sRow[e] != sRow[e - 1]);
        int v = head ? e : 0;
        #pragma unroll
        for (int o = 1; o < 64; o <<= 1) {
            int y = __shfl_up(v, o);
            if (e >= o && y > v) v = y;
        }
        sRid[e] = v;
        sF[e * 3 + 0] = 0.f; sF[e * 3 + 1] = 0.f; sF[e * 3 + 2] = 0.f;
    }

    f32x4 acc[4][2];
    u32 d[4][4];

    // ---- GEMM2: m = silu(t1 @ We2 + be2), K=128 ----
    #pragma unroll
    for (int mt = 0; mt < 4; ++mt)
        #pragma unroll
        for (int r = 0; r < 4; ++r) { acc[mt][0][r] = b2a; acc[mt][1][r] = b2b; }
    #pragma unroll
    for (int c = 0; c < 4; ++c) {
        short8 bf0 = *(const short8*)(We2bf + (c * 8 + w * 2 + 0) * 512 + lane * 8);
        short8 bf1 = *(const short8*)(We2bf + (c * 8 + w * 2 + 1) * 512 + lane * 8);
        #pragma unroll
        for (int mt = 0; mt < 4; ++mt) {
            short8 af = *(const short8*)(sT + (c * 4 + mt) * 512 + lsw);
            acc[mt][0] = __builtin_amdgcn_mfma_f32_16x16x32_bf16(af, bf0, acc[mt][0], 0, 0, 0);
            acc[mt][1] = __builtin_amdgcn_mfma_f32_16x16x32_bf16(af, bf1, acc[mt][1], 0, 0, 0);
        }
    }
    #pragma unroll
    for (int mt = 0; mt < 4; ++mt)
        #pragma unroll
        for (int r = 0; r < 4; ++r)
            d[mt][r] = pkr(siluf(acc[mt][0][r]), siluf(acc[mt][1][r]));
    __syncthreads();   // B2: all sT reads done -> reuse for m
    #pragma unroll
    for (int mt = 0; mt < 4; ++mt) {
        u16* bp = sT + (w * 4 + mt) * 512 + sbase;
        *(u32*)(bp + o0) = d[mt][0];
        *(u32*)(bp + o1) = d[mt][1];
        *(u32*)(bp + o2) = d[mt][2];
        *(u32*)(bp + o3) = d[mt][3];
    }
    __syncthreads();   // B3: m ready

    // ---- GEMM3: u = silu(m @ Wc1 + bc1); coef fused via shfl reduce ----
    #pragma unroll
    for (int mt = 0; mt < 4; ++mt)
        #pragma unroll
        for (int r = 0; r < 4; ++r) { acc[mt][0][r] = b3a; acc[mt][1][r] = b3b; }
    #pragma unroll
    for (int c = 0; c < 4; ++c) {
        short8 bf0 = *(const short8*)(Wc1bf + (c * 8 + w * 2 + 0) * 512 + lane * 8);
        short8 bf1 = *(const short8*)(Wc1bf + (c * 8 + w * 2 + 1) * 512 + lane * 8);
        #pragma unroll
        for (int mt = 0; mt < 4; ++mt) {
            short8 af = *(const short8*)(sT + (c * 4 + mt) * 512 + lsw);
            acc[mt][0] = __builtin_amdgcn_mfma_f32_16x16x32_bf16(af, bf0, acc[mt][0], 0, 0, 0);
            acc[mt][1] = __builtin_amdgcn_mfma_f32_16x16x32_bf16(af, bf1, acc[mt][1], 0, 0, 0);
        }
    }
    #pragma unroll
    for (int mt = 0; mt < 4; ++mt)
        #pragma unroll
        for (int r = 0; r < 4; ++r) {
            float pv = fmaf(siluf(acc[mt][0][r]), wc2a, siluf(acc[mt][1][r]) * wc2b);
            pv += __shfl_xor(pv, 1);
            pv += __shfl_xor(pv, 2);
            pv += __shfl_xor(pv, 4);
            pv += __shfl_xor(pv, 8);
            if (m15 == 0) sCoefP[w][mt * 16 + q * 4 + r] = pv;
        }

    // ---- agg: run-length aggregate m over sorted rows, 1 pk-atomic per run ----
    {
        const int P = tid & 63, C = 2 * P, g = tid >> 6;
        const int xorb = (C >> 3) & 3;
        const int base = ((((C >> 5) * 4 + g) << 9)) + (((C >> 3) & 3) << 7) + (C & 7);
        float s0 = 0.f, s1 = 0.f;
        int prow = sRow[g * 16];
        #pragma unroll
        for (int i = 0; i < 16; ++i) {
            u32 v = *(const u32*)(sT + base + (((i >> 2) & 3) << 5) + (((i & 3) ^ xorb) << 3));
            int r = sRow[g * 16 + i];
            if (r != prow) {
                atomic_pk_add_bf16(aggbf + (size_t)prow * 128 + C, pkr(s0, s1));
                s0 = 0.f; s1 = 0.f; prow = r;
            }
            s0 += bf2f((short)(v & 0xffffu));
            s1 += bf2f((short)(v >> 16));
        }
        atomic_pk_add_bf16(aggbf + (size_t)prow * 128 + C, pkr(s0, s1));
    }
    __syncthreads();   // B4: coef partials + sRid + sF ready

    // force: per-edge clamped tr -> LDS run accumulators -> 1 atomic/(run,ax)
    if (tid < 192) {
        int e = tid / 3, ax = tid - e * 3;
        float coef = sCoefP[0][e] + sCoefP[1][e] + sCoefP[2][e] + sCoefP[3][e];
        float tr = cdiff[(size_t)sEg[e] * 3 + ax] * coef;
        tr = fminf(fmaxf(tr, -100.f), 100.f);
        atomicAdd(&sF[sRid[e] * 3 + ax], tr);
    }
    __syncthreads();   // B5: LDS force sums complete
    if (tid < 192) {
        int e = tid / 3, ax = tid - e * 3;
        if (e == 0 || sRow[e] != sRow[e - 1])
            atomicAdd(&fsum[(size_t)sRow[e] * 3 + ax], sF[e * 3 + ax]);
    }
}

// ---- node kernel: 32 nodes/block (1563 blocks), 4 waves; no vel head ----
__global__ __launch_bounds__(256, 4) void node_kernel(
    const float* __restrict__ h, const u16* __restrict__ hbf, u32 use_ext,
    const float* __restrict__ bn1, const float* __restrict__ bn2,
    const u16* __restrict__ Wn1bf, const u16* __restrict__ Wn2bf,
    const u16* __restrict__ aggbf, const float* __restrict__ fsum,
    const u32* __restrict__ bins, float* __restrict__ out)
{
    __shared__ u16 sX[8192];           // 16KB: 32 nodes x 256 k, slot = r + 32*kg
    __shared__ float sBn1[128], sBn2[128];
    u16* sT = sX + 4096;               // aliases agg half (k=128..255) after GEMM1

    const int tid = threadIdx.x;
    const int nblk = blockIdx.x * 32;
    const int w = tid >> 6;
    const int lane = tid & 63;
    const int m15 = lane & 15, q = lane >> 4;
    const int n0 = w * 32 + 2 * m15, n1 = n0 + 1;
    const int lsw = (lane ^ q) * 8;
    const int a_ = m15 >> 2;
    const int sbase = (a_ << 7) + (q << 5) + ((m15 & 3) << 1);
    const int o0 = (0 ^ a_) << 3, o1 = (1 ^ a_) << 3, o2 = (2 ^ a_) << 3, o3 = (3 ^ a_) << 3;
    const int ard = (m15 + 32 * q) * 8;

    if (tid < 96) {
        int r = tid / 3, ax = tid - r * 3;
        int n = nblk + r;
        if (n < NN)
            out[NN + (size_t)n * 3 + ax] = fsum[(size_t)n * 3 + ax] * __builtin_amdgcn_rcpf(fmaxf((float)bins[n], 1.0f));
    }
    if (tid < 128) { sBn1[tid] = bn1[tid]; sBn2[tid] = bn2[tid]; }

    {
        int r = tid & 31, j = tid >> 5;            // j = 0..7
        int n = nblk + r; if (n > NN - 1) n = NN - 1;
        if (j < 4) {
            if (use_ext) {
                #pragma unroll
                for (int i = 0; i < 4; ++i) {
                    int kg = j * 4 + i;            // 0..15  (h, k=0..127)
                    *(uint4*)&sX[(r + 32 * kg) * 8] =
                        *(const uint4*)(hbf + (size_t)n * 128 + kg * 8);
                }
            } else {
                #pragma unroll
                for (int i = 0; i < 4; ++i) {
                    int kg = j * 4 + i;
                    const float* src = h + (size_t)n * 128 + kg * 8;
                    float4 a = *(const float4*)(src);
                    float4 b = *(const float4*)(src + 4);
                    *(uint4*)&sX[(r + 32 * kg) * 8] = make_uint4(pkr(a.x, a.y), pkr(a.z, a.w),
                                                                 pkr(b.x, b.y), pkr(b.z, b.w));
                }
            }
        } else {
            #pragma unroll
            for (int i = 0; i < 4; ++i) {
                int kg = j * 4 + i;                // 16..31 (agg, k=128..255)
                *(uint4*)&sX[(r + 32 * kg) * 8] =
                    *(const uint4*)(aggbf + (size_t)n * 128 + (kg - 16) * 8);
            }
        }
    }
    __syncthreads();

    f32x4 acc[2][2];

    {
        float b0 = sBn1[n0], b1 = sBn1[n1];
        #pragma unroll
        for (int mt = 0; mt < 2; ++mt)
            #pragma unroll
            for (int r = 0; r < 4; ++r) { acc[mt][0][r] = b0; acc[mt][1][r] = b1; }
    }
    #pragma unroll
    for (int c = 0; c < 8; ++c) {
        short8 bf0 = *(const short8*)(Wn1bf + (c * 8 + w * 2 + 0) * 512 + lane * 8);
        short8 bf1 = *(const short8*)(Wn1bf + (c * 8 + w * 2 + 1) * 512 + lane * 8);
        #pragma unroll
        for (int mt = 0; mt < 2; ++mt) {
            short8 af = *(const short8*)(sX + ard + c * 1024 + mt * 128);
            acc[mt][0] = __builtin_amdgcn_mfma_f32_16x16x32_bf16(af, bf0, acc[mt][0], 0, 0, 0);
            acc[mt][1] = __builtin_amdgcn_mfma_f32_16x16x32_bf16(af, bf1, acc[mt][1], 0, 0, 0);
        }
    }
    u32 dn[2][4];
    #pragma unroll
    for (int mt = 0; mt < 2; ++mt)
        #pragma unroll
        for (int r = 0; r < 4; ++r)
            dn[mt][r] = pkr(siluf(acc[mt][0][r]), siluf(acc[mt][1][r]));
    __syncthreads();
    #pragma unroll
    for (int mt = 0; mt < 2; ++mt) {
        u16* bp = sT + (w * 2 + mt) * 512 + sbase;
        *(u32*)(bp + o0) = dn[mt][0];
        *(u32*)(bp + o1) = dn[mt][1];
        *(u32*)(bp + o2) = dn[mt][2];
        *(u32*)(bp + o3) = dn[mt][3];
    }
    __syncthreads();

    {
        float b0 = sBn2[n0], b1 = sBn2[n1];
        #pragma unroll
        for (int mt = 0; mt < 2; ++mt)
            #pragma unroll
            for (int r = 0; r < 4; ++r) { acc[mt][0][r] = b0; acc[mt][1][r] = b1; }
    }
    #pragma unroll
    for (int c = 0; c < 4; ++c) {
        short8 bf0 = *(const short8*)(Wn2bf + (c * 8 + w * 2 + 0) * 512 + lane * 8);
        short8 bf1 = *(const short8*)(Wn2bf + (c * 8 + w * 2 + 1) * 512 + lane * 8);
        #pragma unroll
        for (int mt = 0; mt < 2; ++mt) {
            short8 af = *(const short8*)(sT + (c * 2 + mt) * 512 + lsw);
            acc[mt][0] = __builtin_amdgcn_mfma_f32_16x16x32_bf16(af, bf0, acc[mt][0], 0, 0, 0);
            acc[mt][1] = __builtin_amdgcn_mfma_f32_16x16x32_bf16(af, bf1, acc[mt][1], 0, 0, 0);
        }
    }
    #pragma unroll
    for (int mt = 0; mt < 2; ++mt)
        #pragma unroll
        for (int r = 0; r < 4; ++r) {
            int n = nblk + mt * 16 + q * 4 + r;
            if (n < NN) {
                f32x2 v; v.x = acc[mt][0][r]; v.y = acc[mt][1][r];
                *(f32x2*)(out + (size_t)4 * NN + (size_t)n * 128 + n0) = v;
            }
        }
}

extern "C" void kernel_launch(void* const* d_in, const int* in_sizes, int n_in,
                              void* d_out, int out_size, void* d_ws, size_t ws_size,
                              hipStream_t stream) {
    const float* h     = (const float*)d_in[0];
    const float* cdiff = (const float*)d_in[1];
    const int* row     = (const int*)d_in[2];
    const int* col     = (const int*)d_in[3];
    const float* We1 = (const float*)d_in[4];
    const float* be1 = (const float*)d_in[5];
    const float* We2 = (const float*)d_in[6];
    const float* be2 = (const float*)d_in[7];
    const float* Wn1 = (const float*)d_in[8];
    const float* bn1 = (const float*)d_in[9];
    const float* Wn2 = (const float*)d_in[10];
    const float* bn2 = (const float*)d_in[11];
    const float* Wc1 = (const float*)d_in[12];
    const float* bc1 = (const float*)d_in[13];
    const float* Wc2 = (const float*)d_in[14];
    const float* Wv1 = (const float*)d_in[15];
    const float* bv1 = (const float*)d_in[16];
    const float* Wv2 = (const float*)d_in[17];
    const float* bv2 = (const float*)d_in[18];

    // base workspace (~26.7MB, verified layout):
    u16* aggbf  = (u16*)d_ws;                           // [NN*128] bf16
    float* fsum = (float*)(aggbf + (size_t)NN * 128);   // [NN*3]
    u32* bins   = (u32*)(fsum + (size_t)NN * 3);        // [NN]
    u16* We1bf = (u16*)(bins + NN);                     // [32768]
    u16* We2bf = We1bf + 32768;                         // [16384]
    u16* Wc1bf = We2bf + 16384;                         // [16384]
    u16* Wn1bf = Wc1bf + 16384;                         // [32768]
    u16* Wn2bf = Wn1bf + 32768;                         // [16384]
    u16* Wv1bf = Wn2bf + 16384;                         // [16384]
    u16* P1bf  = Wv1bf + 16384;                         // [NN*128] bf16
    float* out = (float*)d_out;

    // ws extensions: hbf + rank (39.7MB total; guarded)
    const size_t base_bytes = (size_t)26662144;
    u16* hbf  = (u16*)((char*)d_ws + base_bytes);                     // [NN*128]
    u32* rank = (u32*)((char*)d_ws + base_bytes + (size_t)NN * 256);  // [EE]
    u32 use_ext = (ws_size >= base_bytes + (size_t)NN * 256 + (size_t)EE * 4) ? 1u : 0u;

    // d_out: vel [0,NN) written by pgemm; force region [NN,4NN) hosts sort
    // scratch (cursor+part, 201KB of 600KB) until node overwrites it last.
    u32* cursor = (u32*)(out + NN);                     // [NN]
    u32* part   = cursor + NN;                          // [196]
    // h_out region (25.6MB): P2 (12.8) + edata (12.8) — consumed by edge
    u16* P2bf   = (u16*)(out + (size_t)4 * NN);         // [NN*128]
    u32* edata  = (u32*)(P2bf + (size_t)NN * 128);      // [EE*4] uint4/edge

    size_t zero_bytes = (size_t)NN * 128 * 2 + (size_t)NN * 3 * 4 + (size_t)NN * 4;
    hipMemsetAsync(d_ws, 0, zero_bytes, stream);        // aggbf + fsum + bins

    const int NSC = (NN + 255) / 256;                   // 196 scan blocks

    prephist_kernel<<<512 + (EE + 255) / 256, 256, 0, stream>>>(
        We1, We2, Wc1, Wn1, Wn2, Wv1,
        We1bf, We2bf, Wc1bf, Wn1bf, Wn2bf, Wv1bf,
        row, bins, rank, use_ext);
    scan1_kernel<<<NSC, 256, 0, stream>>>(bins, part);
    scan3_kernel<<<NSC, 256, 0, stream>>>(bins, part, cursor, NSC);
    pgemm_scatter_kernel<<<PGB + (EE + 255) / 256, 256, 0, stream>>>(
        h, be1, bv1, Wv2, bv2,
        We1bf, Wv1bf, P1bf, P2bf,
        hbf, use_ext, out,
        row, col, cdiff, cursor, rank, edata);
    edge_kernel<<<EE / 64, 256, 0, stream>>>(P1bf, P2bf, cdiff, edata,
                                             We1, be2, bc1, Wc2,
                                             We2bf, Wc1bf,
                                             aggbf, fsum);
    node_kernel<<<(NN + 31) / 32, 256, 0, stream>>>(h, hbf, use_ext,
                                                    bn1, bn2,
                                                    Wn1bf, Wn2bf,
                                                    aggbf, fsum, bins, out);
}

// Round 17
// 333.906 us; speedup vs baseline: 1.3357x; 1.0214x over previous
//
#include <hip/hip_runtime.h>

#define NN 50000
#define EE 800000
#define PGB ((NN + 31) / 32)      // 1563 pgemm blocks
#define HB  ((EE + 255) / 256)    // 3125 hist/scatter blocks
#define ZB  3272                  // zero blocks: (NN*256+NN*12)/16/256 rounded up

typedef unsigned short u16;
typedef unsigned int u32;
typedef __attribute__((ext_vector_type(8))) short short8;
typedef __attribute__((ext_vector_type(4))) float f32x4;
typedef __attribute__((ext_vector_type(2))) float f32x2;

__device__ __forceinline__ u16 f2bf(float f) {
    union { float f; u32 i; } v; v.f = f;
    u32 x = v.i;
    return (u16)((x + 0x7fffu + ((x >> 16) & 1u)) >> 16);  // RNE (prep only)
}
// pack two f32 -> bf16 pair (round-half-up): 2 add + 1 v_perm
__device__ __forceinline__ u32 pkr(float lo, float hi) {
    union { float f; u32 i; } a, b; a.f = lo; b.f = hi;
    return __builtin_amdgcn_perm(b.i + 0x8000u, a.i + 0x8000u, 0x07060302u);
}
__device__ __forceinline__ float bf2f(short x) {
    union { u32 i; float f; } v; v.i = ((u32)(u16)x) << 16; return v.f;
}
// silu via hw rcp: avoids IEEE div sequence
__device__ __forceinline__ float siluf(float x) {
    return x * __builtin_amdgcn_rcpf(1.0f + __expf(-x));
}
__device__ __forceinline__ void atomic_pk_add_bf16(u16* addr, u32 data) {
    asm volatile("global_atomic_pk_add_bf16 %0, %1, off" :: "v"(addr), "v"(data) : "memory");
}

// B layout, column-interleaved tiles: group=n>>5, parity=n&1, slot=(n>>1)&15
__device__ __forceinline__ int b_idx2(int k, int n) {
    int chunk = ((k >> 5) << 3) + ((n >> 5) << 1) + (n & 1);
    return chunk * 512 + (((k >> 3) & 3) << 7) + (((n >> 1) & 15) << 3) + (k & 7);
}

// ---- fused prep (0..511) + hist/rank (512..512+HB) + agg/fsum zero (rest) ----
__global__ __launch_bounds__(256) void prephist_kernel(
    const float* __restrict__ We1, const float* __restrict__ We2,
    const float* __restrict__ Wc1, const float* __restrict__ Wn1,
    const float* __restrict__ Wn2, const float* __restrict__ Wv1,
    u16* __restrict__ We1bf, u16* __restrict__ We2bf, u16* __restrict__ Wc1bf,
    u16* __restrict__ Wn1bf, u16* __restrict__ Wn2bf, u16* __restrict__ Wv1bf,
    const int* __restrict__ row, u32* __restrict__ bins,
    u32* __restrict__ rank, u32 use_ext, uint4* __restrict__ zbase)
{
    if (blockIdx.x >= 512 + HB) {
        // zero aggbf+fsum (13.4MB, 837500 uint4s); consumed only by edge/node
        u32 z = (blockIdx.x - (512 + HB)) * 256 + threadIdx.x;
        if (z < 837500u) zbase[z] = make_uint4(0u, 0u, 0u, 0u);
        return;
    }
    if (blockIdx.x >= 512) {
        int e = (blockIdx.x - 512) * 256 + threadIdx.x;
        if (e < EE) {
            u32 rk = atomicAdd(&bins[row[e]], 1u);
            if (use_ext) rank[e] = rk;
        }
        return;
    }
    int i = blockIdx.x * 256 + threadIdx.x;     // 0..131071
    if (i < 32768) {
        int k = i >> 7, n = i & 127;
        We1bf[b_idx2(k, n)] = f2bf(We1[k * 128 + n]);   // rows 0..255
    } else if (i < 49152) {
        int t = i - 32768; int k = t >> 7, n = t & 127;
        We2bf[b_idx2(k, n)] = f2bf(We2[k * 128 + n]);
    } else if (i < 65536) {
        int t = i - 49152; int k = t >> 7, n = t & 127;
        Wc1bf[b_idx2(k, n)] = f2bf(Wc1[k * 128 + n]);
    } else if (i < 98304) {
        int t = i - 65536; int k = t >> 7, n = t & 127;
        Wn1bf[b_idx2(k, n)] = f2bf(Wn1[k * 128 + n]);   // rows 0..255
    } else if (i < 114688) {
        int t = i - 98304; int k = t >> 7, n = t & 127;
        Wn2bf[b_idx2(k, n)] = f2bf(Wn2[k * 128 + n]);
    } else {
        int t = i - 114688; int k = t >> 7, n = t & 127;
        Wv1bf[b_idx2(k, n)] = f2bf(Wv1[k * 128 + n]);
    }
}

__global__ __launch_bounds__(256) void scan1_kernel(const u32* __restrict__ bins,
                                                    u32* __restrict__ part)
{
    __shared__ u32 wsum[4];
    int i = blockIdx.x * 256 + threadIdx.x;
    u32 v = (i < NN) ? bins[i] : 0u;
    #pragma unroll
    for (int o = 1; o < 64; o <<= 1) v += __shfl_xor(v, o);
    if ((threadIdx.x & 63) == 0) wsum[threadIdx.x >> 6] = v;
    __syncthreads();
    if (threadIdx.x == 0) part[blockIdx.x] = wsum[0] + wsum[1] + wsum[2] + wsum[3];
}

// scan3 with scan2 folded in: every block redundantly scans the 196 partials
__global__ __launch_bounds__(256) void scan3_kernel(const u32* __restrict__ bins,
                                                    const u32* __restrict__ part,
                                                    u32* __restrict__ cursor, int np)
{
    __shared__ u32 sPart[256];
    __shared__ u32 wsum[4];
    int t = threadIdx.x;
    sPart[t] = (t < np) ? part[t] : 0u;
    __syncthreads();
    if (t == 0) {
        u32 run = 0;
        for (int i = 0; i < np; ++i) { u32 x = sPart[i]; sPart[i] = run; run += x; }
    }
    int i = blockIdx.x * 256 + t;
    u32 v = (i < NN) ? bins[i] : 0u;
    u32 x = v;
    #pragma unroll
    for (int o = 1; o < 64; o <<= 1) {
        u32 y = __shfl_up(x, o);
        if ((t & 63) >= o) x += y;
    }
    if ((t & 63) == 63) wsum[t >> 6] = x;
    __syncthreads();
    u32 base = sPart[blockIdx.x];
    for (int wv = 0; wv < (t >> 6); ++wv) base += wsum[wv];
    if (i < NN) cursor[i] = base + x - v;   // exclusive prefix
}

// ---- fused: pgemm (blocks 0..PGB-1) | scatter (blocks PGB..) ----
__global__ __launch_bounds__(256, 4) void pgemm_scatter_kernel(
    const float* __restrict__ h, const float* __restrict__ be1,
    const float* __restrict__ bv1, const float* __restrict__ Wv2,
    const float* __restrict__ bv2,
    const u16* __restrict__ We1bf, const u16* __restrict__ Wv1bf,
    u16* __restrict__ P1bf, u16* __restrict__ P2bf,
    u16* __restrict__ hbf, u32 use_ext, float* __restrict__ vel,
    const int* __restrict__ row, const int* __restrict__ col,
    const float* __restrict__ cdiff, u32* __restrict__ cursor,
    const u32* __restrict__ rank, u32* __restrict__ edata)
{
    __shared__ u16 sX[4096];   // 8KB: 32 nodes x 128 k, slot = r + 32*kg
    __shared__ float sVelP[4][32];

    if (blockIdx.x >= PGB) {
        // ---- scatter branch: sorted edata {row, col, rad_bits, orig_e} ----
        int e = (blockIdx.x - PGB) * 256 + threadIdx.x;
        if (e < EE) {
            int r = row[e];
            u32 p = use_ext ? (cursor[r] + rank[e]) : atomicAdd(&cursor[r], 1u);
            float cx = cdiff[(size_t)e * 3 + 0];
            float cy = cdiff[(size_t)e * 3 + 1];
            float cz = cdiff[(size_t)e * 3 + 2];
            float rad = cx * cx + cy * cy + cz * cz;
            uint4 ed;
            ed.x = (u32)r;
            ed.y = (u32)col[e];
            ed.z = __float_as_uint(rad);
            ed.w = (u32)e;
            *(uint4*)(edata + (size_t)p * 4) = ed;
        }
        return;
    }

    const int tid = threadIdx.x;
    const int nblk = blockIdx.x * 32;
    const int w = tid >> 6;
    const int lane = tid & 63;
    const int m15 = lane & 15, q = lane >> 4;
    const int n0 = w * 32 + 2 * m15, n1 = n0 + 1;
    const int ard = (m15 + 32 * q) * 8;
    const float b0 = be1[n0], b1 = be1[n1];

    {
        int r = tid & 31, j = tid >> 5;          // j = 0..7
        int n = nblk + r; if (n > NN - 1) n = NN - 1;
        #pragma unroll
        for (int i = 0; i < 2; ++i) {
            int kg = j * 2 + i;                  // 0..15
            const float* src = h + (size_t)n * 128 + kg * 8;
            float4 a = *(const float4*)(src);
            float4 b = *(const float4*)(src + 4);
            uint4 v = make_uint4(pkr(a.x, a.y), pkr(a.z, a.w),
                                 pkr(b.x, b.y), pkr(b.z, b.w));
            *(uint4*)&sX[(r + 32 * kg) * 8] = v;
            if (use_ext)
                *(uint4*)(hbf + (size_t)n * 128 + kg * 8) = v;
        }
    }
    __syncthreads();

    f32x4 acc[2][2];

    // P1: We1 k-rows 0..127 (chunks c=0..3), bias be1 folded
    #pragma unroll
    for (int mt = 0; mt < 2; ++mt)
        #pragma unroll
        for (int r = 0; r < 4; ++r) { acc[mt][0][r] = b0; acc[mt][1][r] = b1; }
    #pragma unroll
    for (int c = 0; c < 4; ++c) {
        short8 bf0 = *(const short8*)(We1bf + (c * 8 + w * 2 + 0) * 512 + lane * 8);
        short8 bf1 = *(const short8*)(We1bf + (c * 8 + w * 2 + 1) * 512 + lane * 8);
        #pragma unroll
        for (int mt = 0; mt < 2; ++mt) {
            short8 af = *(const short8*)(sX + ard + c * 1024 + mt * 128);
            acc[mt][0] = __builtin_amdgcn_mfma_f32_16x16x32_bf16(af, bf0, acc[mt][0], 0, 0, 0);
            acc[mt][1] = __builtin_amdgcn_mfma_f32_16x16x32_bf16(af, bf1, acc[mt][1], 0, 0, 0);
        }
    }
    #pragma unroll
    for (int mt = 0; mt < 2; ++mt)
        #pragma unroll
        for (int r = 0; r < 4; ++r) {
            int n = nblk + mt * 16 + q * 4 + r;
            if (n < NN)
                *(u32*)(P1bf + (size_t)n * 128 + n0) = pkr(acc[mt][0][r], acc[mt][1][r]);
        }

    // P2: We1 k-rows 128..255 (chunks c=4..7), no bias; same A tile
    #pragma unroll
    for (int mt = 0; mt < 2; ++mt)
        #pragma unroll
        for (int r = 0; r < 4; ++r) { acc[mt][0][r] = 0.0f; acc[mt][1][r] = 0.0f; }
    #pragma unroll
    for (int c = 4; c < 8; ++c) {
        short8 bf0 = *(const short8*)(We1bf + (c * 8 + w * 2 + 0) * 512 + lane * 8);
        short8 bf1 = *(const short8*)(We1bf + (c * 8 + w * 2 + 1) * 512 + lane * 8);
        #pragma unroll
        for (int mt = 0; mt < 2; ++mt) {
            short8 af = *(const short8*)(sX + ard + (c - 4) * 1024 + mt * 128);
            acc[mt][0] = __builtin_amdgcn_mfma_f32_16x16x32_bf16(af, bf0, acc[mt][0], 0, 0, 0);
            acc[mt][1] = __builtin_amdgcn_mfma_f32_16x16x32_bf16(af, bf1, acc[mt][1], 0, 0, 0);
        }
    }
    #pragma unroll
    for (int mt = 0; mt < 2; ++mt)
        #pragma unroll
        for (int r = 0; r < 4; ++r) {
            int n = nblk + mt * 16 + q * 4 + r;
            if (n < NN)
                *(u32*)(P2bf + (size_t)n * 128 + n0) = pkr(acc[mt][0][r], acc[mt][1][r]);
        }

    // ---- vel head: vel = silu(h@Wv1+bv1)@Wv2 + bv2 (reuses staged h) ----
    {
        const float bva = bv1[n0], bvb = bv1[n1];
        const float wv2a = Wv2[n0], wv2b = Wv2[n1];
        #pragma unroll
        for (int mt = 0; mt < 2; ++mt)
            #pragma unroll
            for (int r = 0; r < 4; ++r) { acc[mt][0][r] = bva; acc[mt][1][r] = bvb; }
        #pragma unroll
        for (int c = 0; c < 4; ++c) {
            short8 bf0 = *(const short8*)(Wv1bf + (c * 8 + w * 2 + 0) * 512 + lane * 8);
            short8 bf1 = *(const short8*)(Wv1bf + (c * 8 + w * 2 + 1) * 512 + lane * 8);
            #pragma unroll
            for (int mt = 0; mt < 2; ++mt) {
                short8 af = *(const short8*)(sX + ard + c * 1024 + mt * 128);
                acc[mt][0] = __builtin_amdgcn_mfma_f32_16x16x32_bf16(af, bf0, acc[mt][0], 0, 0, 0);
                acc[mt][1] = __builtin_amdgcn_mfma_f32_16x16x32_bf16(af, bf1, acc[mt][1], 0, 0, 0);
            }
        }
        #pragma unroll
        for (int mt = 0; mt < 2; ++mt)
            #pragma unroll
            for (int r = 0; r < 4; ++r) {
                float pv = fmaf(siluf(acc[mt][0][r]), wv2a, siluf(acc[mt][1][r]) * wv2b);
                pv += __shfl_xor(pv, 1);
                pv += __shfl_xor(pv, 2);
                pv += __shfl_xor(pv, 4);
                pv += __shfl_xor(pv, 8);
                if (m15 == 0) sVelP[w][mt * 16 + q * 4 + r] = pv;
            }
        __syncthreads();
        if (tid < 32) {
            int n = nblk + tid;
            if (n < NN)
                vel[n] = bv2[0] + sVelP[0][tid] + sVelP[1][tid] + sVelP[2][tid] + sVelP[3][tid];
        }
    }
}

// ---- edge kernel: R13-proven body + XCD-aware bijective block swizzle ----
__global__ __launch_bounds__(256, 8) void edge_kernel(
    const u16* __restrict__ P1bf, const u16* __restrict__ P2bf,
    const float* __restrict__ cdiff,
    const u32* __restrict__ edata,
    const float* __restrict__ We1,      // only row 256 (radial weights) used
    const float* __restrict__ be2, const float* __restrict__ bc1,
    const float* __restrict__ Wc2,
    const u16* __restrict__ We2bf, const u16* __restrict__ Wc1bf,
    u16* __restrict__ aggbf, float* __restrict__ fsum)
{
    __shared__ u16 sT[8192];        // 16KB swizzled A-fragment buffer (t1, then m)
    __shared__ int sRow[64];
    __shared__ int sEg[64];
    __shared__ int sRid[64];        // run-head index per edge (sorted rows)
    __shared__ float sCoefP[4][64];
    __shared__ float sF[192];       // per-run force accumulators [rid*3+ax]

    const int tid = threadIdx.x;
    // bijective XCD swizzle (nwg = EE/64 = 12500, 8 XCDs)
    const int xcd = blockIdx.x & 7, off = blockIdx.x >> 3;
    const int qq = 12500 >> 3, rr = 12500 & 7;      // 1562, 4
    const int lb = (xcd < rr ? xcd * (qq + 1) : rr * (qq + 1) + (xcd - rr) * qq) + off;
    const int e0 = lb * 64;
    const int w = tid >> 6;
    const int lane = tid & 63;
    const int m15 = lane & 15, q = lane >> 4;
    const int n0 = w * 32 + 2 * m15, n1 = n0 + 1;
    const int lsw = (lane ^ q) * 8;
    const int a_ = m15 >> 2;
    const int sbase = (a_ << 7) + (q << 5) + ((m15 & 3) << 1);
    const int o0 = (0 ^ a_) << 3, o1 = (1 ^ a_) << 3, o2 = (2 ^ a_) << 3, o3 = (3 ^ a_) << 3;

    const float b2a = be2[n0], b2b = be2[n1];
    const float b3a = bc1[n0], b3b = bc1[n1];
    const float wc2a = Wc2[n0], wc2b = Wc2[n1];

    // t1 = silu(P1[row] + P2[col] + rad*We1[256]) -> swizzled sT
    {
        int e = tid & 63, seg = tid >> 6;
        uint4 ed = *(const uint4*)(edata + (size_t)(e0 + e) * 4);
        int nr = (int)ed.x, nc = (int)ed.y;
        float rad = __uint_as_float(ed.z);
        if (seg == 0) { sRow[e] = nr; sEg[e] = (int)ed.w; }
        const u16* p1 = P1bf + (size_t)nr * 128 + seg * 32;
        const u16* p2 = P2bf + (size_t)nc * 128 + seg * 32;
        const float* wr = We1 + 256 * 128 + seg * 32;
        u16* tb = sT + (((seg * 4 + (e >> 4)) << 9) + (((e >> 2) & 3) << 5));
        const int rl = e & 3;
        #pragma unroll 2
        for (int g = 0; g < 4; ++g) {
            short8 x1 = *(const short8*)(p1 + g * 8);
            short8 x2 = *(const short8*)(p2 + g * 8);
            float4 wa = *(const float4*)(wr + g * 8);
            float4 wb = *(const float4*)(wr + g * 8 + 4);
            float v[8];
            #pragma unroll
            for (int t = 0; t < 4; ++t) {
                v[t]     = siluf(bf2f(x1[t])     + bf2f(x2[t])     + rad * ((const float*)&wa)[t]);
                v[t + 4] = siluf(bf2f(x1[t + 4]) + bf2f(x2[t + 4]) + rad * ((const float*)&wb)[t]);
            }
            uint4 dd = make_uint4(pkr(v[0], v[1]), pkr(v[2], v[3]),
                                  pkr(v[4], v[5]), pkr(v[6], v[7]));
            *(uint4*)(tb + ((g << 7) + ((rl ^ g) << 3))) = dd;
        }
    }
    __syncthreads();   // B1: t1 + sRow ready

    // run-head ids via 6-step max-scan (wave 0); zero force accumulators
    if (tid < 64) {
        int e = tid;
        int head = (e == 0) || (sRow[e] != sRow[e - 1]);
        int v = head ? e : 0;
        #pragma unroll
        for (int o = 1; o < 64; o <<= 1) {
            int y = __shfl_up(v, o);
            if (e >= o && y > v) v = y;
        }
        sRid[e] = v;
        sF[e * 3 + 0] = 0.f; sF[e * 3 + 1] = 0.f; sF[e * 3 + 2] = 0.f;
    }

    f32x4 acc[4][2];
    u32 d[4][4];

    // ---- GEMM2: m = silu(t1 @ We2 + be2), K=128 ----
    #pragma unroll
    for (int mt = 0; mt < 4; ++mt)
        #pragma unroll
        for (int r = 0; r < 4; ++r) { acc[mt][0][r] = b2a; acc[mt][1][r] = b2b; }
    #pragma unroll
    for (int c = 0; c < 4; ++c) {
        short8 bf0 = *(const short8*)(We2bf + (c * 8 + w * 2 + 0) * 512 + lane * 8);
        short8 bf1 = *(const short8*)(We2bf + (c * 8 + w * 2 + 1) * 512 + lane * 8);
        #pragma unroll
        for (int mt = 0; mt < 4; ++mt) {
            short8 af = *(const short8*)(sT + (c * 4 + mt) * 512 + lsw);
            acc[mt][0] = __builtin_amdgcn_mfma_f32_16x16x32_bf16(af, bf0, acc[mt][0], 0, 0, 0);
            acc[mt][1] = __builtin_amdgcn_mfma_f32_16x16x32_bf16(af, bf1, acc[mt][1], 0, 0, 0);
        }
    }
    #pragma unroll
    for (int mt = 0; mt < 4; ++mt)
        #pragma unroll
        for (int r = 0; r < 4; ++r)
            d[mt][r] = pkr(siluf(acc[mt][0][r]), siluf(acc[mt][1][r]));
    __syncthreads();   // B2: all sT reads done -> reuse for m
    #pragma unroll
    for (int mt = 0; mt < 4; ++mt) {
        u16* bp = sT + (w * 4 + mt) * 512 + sbase;
        *(u32*)(bp + o0) = d[mt][0];
        *(u32*)(bp + o1) = d[mt][1];
        *(u32*)(bp + o2) = d[mt][2];
        *(u32*)(bp + o3) = d[mt][3];
    }
    __syncthreads();   // B3: m ready

    // ---- GEMM3: u = silu(m @ Wc1 + bc1); coef fused via shfl reduce ----
    #pragma unroll
    for (int mt = 0; mt < 4; ++mt)
        #pragma unroll
        for (int r = 0; r < 4; ++r) { acc[mt][0][r] = b3a; acc[mt][1][r] = b3b; }
    #pragma unroll
    for (int c = 0; c < 4; ++c) {
        short8 bf0 = *(const short8*)(Wc1bf + (c * 8 + w * 2 + 0) * 512 + lane * 8);
        short8 bf1 = *(const short8*)(Wc1bf + (c * 8 + w * 2 + 1) * 512 + lane * 8);
        #pragma unroll
        for (int mt = 0; mt < 4; ++mt) {
            short8 af = *(const short8*)(sT + (c * 4 + mt) * 512 + lsw);
            acc[mt][0] = __builtin_amdgcn_mfma_f32_16x16x32_bf16(af, bf0, acc[mt][0], 0, 0, 0);
            acc[mt][1] = __builtin_amdgcn_mfma_f32_16x16x32_bf16(af, bf1, acc[mt][1], 0, 0, 0);
        }
    }
    #pragma unroll
    for (int mt = 0; mt < 4; ++mt)
        #pragma unroll
        for (int r = 0; r < 4; ++r) {
            float pv = fmaf(siluf(acc[mt][0][r]), wc2a, siluf(acc[mt][1][r]) * wc2b);
            pv += __shfl_xor(pv, 1);
            pv += __shfl_xor(pv, 2);
            pv += __shfl_xor(pv, 4);
            pv += __shfl_xor(pv, 8);
            if (m15 == 0) sCoefP[w][mt * 16 + q * 4 + r] = pv;
        }

    // ---- agg: run-length aggregate m over sorted rows, 1 pk-atomic per run ----
    {
        const int P = tid & 63, C = 2 * P, g = tid >> 6;
        const int xorb = (C >> 3) & 3;
        const int base = ((((C >> 5) * 4 + g) << 9)) + (((C >> 3) & 3) << 7) + (C & 7);
        float s0 = 0.f, s1 = 0.f;
        int prow = sRow[g * 16];
        #pragma unroll
        for (int i = 0; i < 16; ++i) {
            u32 v = *(const u32*)(sT + base + (((i >> 2) & 3) << 5) + (((i & 3) ^ xorb) << 3));
            int r = sRow[g * 16 + i];
            if (r != prow) {
                atomic_pk_add_bf16(aggbf + (size_t)prow * 128 + C, pkr(s0, s1));
                s0 = 0.f; s1 = 0.f; prow = r;
            }
            s0 += bf2f((short)(v & 0xffffu));
            s1 += bf2f((short)(v >> 16));
        }
        atomic_pk_add_bf16(aggbf + (size_t)prow * 128 + C, pkr(s0, s1));
    }
    __syncthreads();   // B4: coef partials + sRid + sF ready

    // force: per-edge clamped tr -> LDS run accumulators -> 1 atomic/(run,ax)
    if (tid < 192) {
        int e = tid / 3, ax = tid - e * 3;
        float coef = sCoefP[0][e] + sCoefP[1][e] + sCoefP[2][e] + sCoefP[3][e];
        float tr = cdiff[(size_t)sEg[e] * 3 + ax] * coef;
        tr = fminf(fmaxf(tr, -100.f), 100.f);
        atomicAdd(&sF[sRid[e] * 3 + ax], tr);
    }
    __syncthreads();   // B5: LDS force sums complete
    if (tid < 192) {
        int e = tid / 3, ax = tid - e * 3;
        if (e == 0 || sRow[e] != sRow[e - 1])
            atomicAdd(&fsum[(size_t)sRow[e] * 3 + ax], sF[e * 3 + ax]);
    }
}

// ---- node kernel: 32 nodes/block (1563 blocks), 4 waves; no vel head ----
__global__ __launch_bounds__(256, 4) void node_kernel(
    const float* __restrict__ h, const u16* __restrict__ hbf, u32 use_ext,
    const float* __restrict__ bn1, const float* __restrict__ bn2,
    const u16* __restrict__ Wn1bf, const u16* __restrict__ Wn2bf,
    const u16* __restrict__ aggbf, const float* __restrict__ fsum,
    const u32* __restrict__ bins, float* __restrict__ out)
{
    __shared__ u16 sX[8192];           // 16KB: 32 nodes x 256 k, slot = r + 32*kg
    __shared__ float sBn1[128], sBn2[128];
    u16* sT = sX + 4096;               // aliases agg half (k=128..255) after GEMM1

    const int tid = threadIdx.x;
    const int nblk = blockIdx.x * 32;
    const int w = tid >> 6;
    const int lane = tid & 63;
    const int m15 = lane & 15, q = lane >> 4;
    const int n0 = w * 32 + 2 * m15, n1 = n0 + 1;
    const int lsw = (lane ^ q) * 8;
    const int a_ = m15 >> 2;
    const int sbase = (a_ << 7) + (q << 5) + ((m15 & 3) << 1);
    const int o0 = (0 ^ a_) << 3, o1 = (1 ^ a_) << 3, o2 = (2 ^ a_) << 3, o3 = (3 ^ a_) << 3;
    const int ard = (m15 + 32 * q) * 8;

    if (tid < 96) {
        int r = tid / 3, ax = tid - r * 3;
        int n = nblk + r;
        if (n < NN)
            out[NN + (size_t)n * 3 + ax] = fsum[(size_t)n * 3 + ax] * __builtin_amdgcn_rcpf(fmaxf((float)bins[n], 1.0f));
    }
    if (tid < 128) { sBn1[tid] = bn1[tid]; sBn2[tid] = bn2[tid]; }

    {
        int r = tid & 31, j = tid >> 5;            // j = 0..7
        int n = nblk + r; if (n > NN - 1) n = NN - 1;
        if (j < 4) {
            if (use_ext) {
                #pragma unroll
                for (int i = 0; i < 4; ++i) {
                    int kg = j * 4 + i;            // 0..15  (h, k=0..127)
                    *(uint4*)&sX[(r + 32 * kg) * 8] =
                        *(const uint4*)(hbf + (size_t)n * 128 + kg * 8);
                }
            } else {
                #pragma unroll
                for (int i = 0; i < 4; ++i) {
                    int kg = j * 4 + i;
                    const float* src = h + (size_t)n * 128 + kg * 8;
                    float4 a = *(const float4*)(src);
                    float4 b = *(const float4*)(src + 4);
                    *(uint4*)&sX[(r + 32 * kg) * 8] = make_uint4(pkr(a.x, a.y), pkr(a.z, a.w),
                                                                 pkr(b.x, b.y), pkr(b.z, b.w));
                }
            }
        } else {
            #pragma unroll
            for (int i = 0; i < 4; ++i) {
                int kg = j * 4 + i;                // 16..31 (agg, k=128..255)
                *(uint4*)&sX[(r + 32 * kg) * 8] =
                    *(const uint4*)(aggbf + (size_t)n * 128 + (kg - 16) * 8);
            }
        }
    }
    __syncthreads();

    f32x4 acc[2][2];

    {
        float b0 = sBn1[n0], b1 = sBn1[n1];
        #pragma unroll
        for (int mt = 0; mt < 2; ++mt)
            #pragma unroll
            for (int r = 0; r < 4; ++r) { acc[mt][0][r] = b0; acc[mt][1][r] = b1; }
    }
    #pragma unroll
    for (int c = 0; c < 8; ++c) {
        short8 bf0 = *(const short8*)(Wn1bf + (c * 8 + w * 2 + 0) * 512 + lane * 8);
        short8 bf1 = *(const short8*)(Wn1bf + (c * 8 + w * 2 + 1) * 512 + lane * 8);
        #pragma unroll
        for (int mt = 0; mt < 2; ++mt) {
            short8 af = *(const short8*)(sX + ard + c * 1024 + mt * 128);
            acc[mt][0] = __builtin_amdgcn_mfma_f32_16x16x32_bf16(af, bf0, acc[mt][0], 0, 0, 0);
            acc[mt][1] = __builtin_amdgcn_mfma_f32_16x16x32_bf16(af, bf1, acc[mt][1], 0, 0, 0);
        }
    }
    u32 dn[2][4];
    #pragma unroll
    for (int mt = 0; mt < 2; ++mt)
        #pragma unroll
        for (int r = 0; r < 4; ++r)
            dn[mt][r] = pkr(siluf(acc[mt][0][r]), siluf(acc[mt][1][r]));
    __syncthreads();
    #pragma unroll
    for (int mt = 0; mt < 2; ++mt) {
        u16* bp = sT + (w * 2 + mt) * 512 + sbase;
        *(u32*)(bp + o0) = dn[mt][0];
        *(u32*)(bp + o1) = dn[mt][1];
        *(u32*)(bp + o2) = dn[mt][2];
        *(u32*)(bp + o3) = dn[mt][3];
    }
    __syncthreads();

    {
        float b0 = sBn2[n0], b1 = sBn2[n1];
        #pragma unroll
        for (int mt = 0; mt < 2; ++mt)
            #pragma unroll
            for (int r = 0; r < 4; ++r) { acc[mt][0][r] = b0; acc[mt][1][r] = b1; }
    }
    #pragma unroll
    for (int c = 0; c < 4; ++c) {
        short8 bf0 = *(const short8*)(Wn2bf + (c * 8 + w * 2 + 0) * 512 + lane * 8);
        short8 bf1 = *(const short8*)(Wn2bf + (c * 8 + w * 2 + 1) * 512 + lane * 8);
        #pragma unroll
        for (int mt = 0; mt < 2; ++mt) {
            short8 af = *(const short8*)(sT + (c * 2 + mt) * 512 + lsw);
            acc[mt][0] = __builtin_amdgcn_mfma_f32_16x16x32_bf16(af, bf0, acc[mt][0], 0, 0, 0);
            acc[mt][1] = __builtin_amdgcn_mfma_f32_16x16x32_bf16(af, bf1, acc[mt][1], 0, 0, 0);
        }
    }
    #pragma unroll
    for (int mt = 0; mt < 2; ++mt)
        #pragma unroll
        for (int r = 0; r < 4; ++r) {
            int n = nblk + mt * 16 + q * 4 + r;
            if (n < NN) {
                f32x2 v; v.x = acc[mt][0][r]; v.y = acc[mt][1][r];
                *(f32x2*)(out + (size_t)4 * NN + (size_t)n * 128 + n0) = v;
            }
        }
}

extern "C" void kernel_launch(void* const* d_in, const int* in_sizes, int n_in,
                              void* d_out, int out_size, void* d_ws, size_t ws_size,
                              hipStream_t stream) {
    const float* h     = (const float*)d_in[0];
    const float* cdiff = (const float*)d_in[1];
    const int* row     = (const int*)d_in[2];
    const int* col     = (const int*)d_in[3];
    const float* We1 = (const float*)d_in[4];
    const float* be1 = (const float*)d_in[5];
    const float* We2 = (const float*)d_in[6];
    const float* be2 = (const float*)d_in[7];
    const float* Wn1 = (const float*)d_in[8];
    const float* bn1 = (const float*)d_in[9];
    const float* Wn2 = (const float*)d_in[10];
    const float* bn2 = (const float*)d_in[11];
    const float* Wc1 = (const float*)d_in[12];
    const float* bc1 = (const float*)d_in[13];
    const float* Wc2 = (const float*)d_in[14];
    const float* Wv1 = (const float*)d_in[15];
    const float* bv1 = (const float*)d_in[16];
    const float* Wv2 = (const float*)d_in[17];
    const float* bv2 = (const float*)d_in[18];

    // base workspace (~26.7MB, verified layout):
    u16* aggbf  = (u16*)d_ws;                           // [NN*128] bf16
    float* fsum = (float*)(aggbf + (size_t)NN * 128);   // [NN*3]
    u32* bins   = (u32*)(fsum + (size_t)NN * 3);        // [NN]
    u16* We1bf = (u16*)(bins + NN);                     // [32768]
    u16* We2bf = We1bf + 32768;                         // [16384]
    u16* Wc1bf = We2bf + 16384;                         // [16384]
    u16* Wn1bf = Wc1bf + 16384;                         // [32768]
    u16* Wn2bf = Wn1bf + 32768;                         // [16384]
    u16* Wv1bf = Wn2bf + 16384;                         // [16384]
    u16* P1bf  = Wv1bf + 16384;                         // [NN*128] bf16
    float* out = (float*)d_out;

    // ws extensions: hbf + rank (39.7MB total; guarded)
    const size_t base_bytes = (size_t)26662144;
    u16* hbf  = (u16*)((char*)d_ws + base_bytes);                     // [NN*128]
    u32* rank = (u32*)((char*)d_ws + base_bytes + (size_t)NN * 256);  // [EE]
    u32 use_ext = (ws_size >= base_bytes + (size_t)NN * 256 + (size_t)EE * 4) ? 1u : 0u;

    // d_out: vel [0,NN) written by pgemm; force region [NN,4NN) hosts sort
    // scratch (cursor+part, 201KB of 600KB) until node overwrites it last.
    u32* cursor = (u32*)(out + NN);                     // [NN]
    u32* part   = cursor + NN;                          // [196]
    // h_out region (25.6MB): P2 (12.8) + edata (12.8) — consumed by edge
    u16* P2bf   = (u16*)(out + (size_t)4 * NN);         // [NN*128]
    u32* edata  = (u32*)(P2bf + (size_t)NN * 128);      // [EE*4] uint4/edge

    // bins only (200KB): aggbf+fsum zeroing is fused into prephist (same-launch
    // hist atomics forbid fusing bins zeroing — no inter-block ordering).
    hipMemsetAsync(bins, 0, (size_t)NN * 4, stream);

    const int NSC = (NN + 255) / 256;                   // 196 scan blocks

    prephist_kernel<<<512 + HB + ZB, 256, 0, stream>>>(
        We1, We2, Wc1, Wn1, Wn2, Wv1,
        We1bf, We2bf, Wc1bf, Wn1bf, Wn2bf, Wv1bf,
        row, bins, rank, use_ext, (uint4*)d_ws);
    scan1_kernel<<<NSC, 256, 0, stream>>>(bins, part);
    scan3_kernel<<<NSC, 256, 0, stream>>>(bins, part, cursor, NSC);
    pgemm_scatter_kernel<<<PGB + HB, 256, 0, stream>>>(
        h, be1, bv1, Wv2, bv2,
        We1bf, Wv1bf, P1bf, P2bf,
        hbf, use_ext, out,
        row, col, cdiff, cursor, rank, edata);
    edge_kernel<<<EE / 64, 256, 0, stream>>>(P1bf, P2bf, cdiff, edata,
                                             We1, be2, bc1, Wc2,
                                             We2bf, Wc1bf,
                                             aggbf, fsum);
    node_kernel<<<(NN + 31) / 32, 256, 0, stream>>>(h, hbf, use_ext,
                                                    bn1, bn2,
                                                    Wn1bf, Wn2bf,
                                                    aggbf, fsum, bins, out);
}

// Round 20
// 327.588 us; speedup vs baseline: 1.3615x; 1.0193x over previous
//
#include <hip/hip_runtime.h>

#define NN 50000
#define EE 800000
#define PGB ((NN + 31) / 32)      // 1563 pgemm blocks
#define HB  ((EE + 255) / 256)    // 3125 hist/scatter blocks
#define ZB  3272                  // zero blocks: (NN*256+NN*12)/16/256 rounded up

typedef unsigned short u16;
typedef unsigned int u32;
typedef __attribute__((ext_vector_type(8))) short short8;
typedef __attribute__((ext_vector_type(4))) float f32x4;
typedef __attribute__((ext_vector_type(2))) float f32x2;

__device__ __forceinline__ u16 f2bf(float f) {
    union { float f; u32 i; } v; v.f = f;
    u32 x = v.i;
    return (u16)((x + 0x7fffu + ((x >> 16) & 1u)) >> 16);  // RNE (prep only)
}
// pack two f32 -> bf16 pair (round-half-up): 2 add + 1 v_perm
// (R18 lesson: v_cvt_pk_bf16_f32 asm does NOT match these semantics — keep this.)
__device__ __forceinline__ u32 pkr(float lo, float hi) {
    union { float f; u32 i; } a, b; a.f = lo; b.f = hi;
    return __builtin_amdgcn_perm(b.i + 0x8000u, a.i + 0x8000u, 0x07060302u);
}
__device__ __forceinline__ float bf2f(short x) {
    union { u32 i; float f; } v; v.i = ((u32)(u16)x) << 16; return v.f;
}
// silu via hw rcp: avoids IEEE div sequence
__device__ __forceinline__ float siluf(float x) {
    return x * __builtin_amdgcn_rcpf(1.0f + __expf(-x));
}
__device__ __forceinline__ void atomic_pk_add_bf16(u16* addr, u32 data) {
    asm volatile("global_atomic_pk_add_bf16 %0, %1, off" :: "v"(addr), "v"(data) : "memory");
}

// B layout, column-interleaved tiles: group=n>>5, parity=n&1, slot=(n>>1)&15
__device__ __forceinline__ int b_idx2(int k, int n) {
    int chunk = ((k >> 5) << 3) + ((n >> 5) << 1) + (n & 1);
    return chunk * 512 + (((k >> 3) & 3) << 7) + (((n >> 1) & 15) << 3) + (k & 7);
}

// ---- fused prep (0..511) + hist/rank (512..512+HB) + agg/fsum zero (rest) ----
__global__ __launch_bounds__(256) void prephist_kernel(
    const float* __restrict__ We1, const float* __restrict__ We2,
    const float* __restrict__ Wc1, const float* __restrict__ Wn1,
    const float* __restrict__ Wn2, const float* __restrict__ Wv1,
    u16* __restrict__ We1bf, u16* __restrict__ We2bf, u16* __restrict__ Wc1bf,
    u16* __restrict__ Wn1bf, u16* __restrict__ Wn2bf, u16* __restrict__ Wv1bf,
    const int* __restrict__ row, u32* __restrict__ bins,
    u32* __restrict__ rank, u32 use_ext, uint4* __restrict__ zbase)
{
    if (blockIdx.x >= 512 + HB) {
        // zero aggbf+fsum (13.4MB, 837500 uint4s); consumed only by edge/node
        u32 z = (blockIdx.x - (512 + HB)) * 256 + threadIdx.x;
        if (z < 837500u) zbase[z] = make_uint4(0u, 0u, 0u, 0u);
        return;
    }
    if (blockIdx.x >= 512) {
        int e = (blockIdx.x - 512) * 256 + threadIdx.x;
        if (e < EE) {
            u32 rk = atomicAdd(&bins[row[e]], 1u);
            if (use_ext) rank[e] = rk;
        }
        return;
    }
    int i = blockIdx.x * 256 + threadIdx.x;     // 0..131071
    if (i < 32768) {
        int k = i >> 7, n = i & 127;
        We1bf[b_idx2(k, n)] = f2bf(We1[k * 128 + n]);   // rows 0..255
    } else if (i < 49152) {
        int t = i - 32768; int k = t >> 7, n = t & 127;
        We2bf[b_idx2(k, n)] = f2bf(We2[k * 128 + n]);
    } else if (i < 65536) {
        int t = i - 49152; int k = t >> 7, n = t & 127;
        Wc1bf[b_idx2(k, n)] = f2bf(Wc1[k * 128 + n]);
    } else if (i < 98304) {
        int t = i - 65536; int k = t >> 7, n = t & 127;
        Wn1bf[b_idx2(k, n)] = f2bf(Wn1[k * 128 + n]);   // rows 0..255
    } else if (i < 114688) {
        int t = i - 98304; int k = t >> 7, n = t & 127;
        Wn2bf[b_idx2(k, n)] = f2bf(Wn2[k * 128 + n]);
    } else {
        int t = i - 114688; int k = t >> 7, n = t & 127;
        Wv1bf[b_idx2(k, n)] = f2bf(Wv1[k * 128 + n]);
    }
}

__global__ __launch_bounds__(256) void scan1_kernel(const u32* __restrict__ bins,
                                                    u32* __restrict__ part)
{
    __shared__ u32 wsum[4];
    int i = blockIdx.x * 256 + threadIdx.x;
    u32 v = (i < NN) ? bins[i] : 0u;
    #pragma unroll
    for (int o = 1; o < 64; o <<= 1) v += __shfl_xor(v, o);
    if ((threadIdx.x & 63) == 0) wsum[threadIdx.x >> 6] = v;
    __syncthreads();
    if (threadIdx.x == 0) part[blockIdx.x] = wsum[0] + wsum[1] + wsum[2] + wsum[3];
}

// scan3 with scan2 folded in: every block redundantly scans the 196 partials
__global__ __launch_bounds__(256) void scan3_kernel(const u32* __restrict__ bins,
                                                    const u32* __restrict__ part,
                                                    u32* __restrict__ cursor, int np)
{
    __shared__ u32 sPart[256];
    __shared__ u32 wsum[4];
    int t = threadIdx.x;
    sPart[t] = (t < np) ? part[t] : 0u;
    __syncthreads();
    if (t == 0) {
        u32 run = 0;
        for (int i = 0; i < np; ++i) { u32 x = sPart[i]; sPart[i] = run; run += x; }
    }
    int i = blockIdx.x * 256 + t;
    u32 v = (i < NN) ? bins[i] : 0u;
    u32 x = v;
    #pragma unroll
    for (int o = 1; o < 64; o <<= 1) {
        u32 y = __shfl_up(x, o);
        if ((t & 63) >= o) x += y;
    }
    if ((t & 63) == 63) wsum[t >> 6] = x;
    __syncthreads();
    u32 base = sPart[blockIdx.x];
    for (int wv = 0; wv < (t >> 6); ++wv) base += wsum[wv];
    if (i < NN) cursor[i] = base + x - v;   // exclusive prefix
}

// ---- fused: pgemm (blocks 0..PGB-1) | scatter (blocks PGB..) ----
__global__ __launch_bounds__(256, 4) void pgemm_scatter_kernel(
    const float* __restrict__ h, const float* __restrict__ be1,
    const float* __restrict__ bv1, const float* __restrict__ Wv2,
    const float* __restrict__ bv2,
    const u16* __restrict__ We1bf, const u16* __restrict__ Wv1bf,
    u16* __restrict__ P1bf, u16* __restrict__ P2bf,
    u16* __restrict__ hbf, u32 use_ext, float* __restrict__ vel,
    const int* __restrict__ row, const int* __restrict__ col,
    const float* __restrict__ cdiff, u32* __restrict__ cursor,
    const u32* __restrict__ rank, u32* __restrict__ edata)
{
    __shared__ u16 sX[4096];   // 8KB: 32 nodes x 128 k, slot = r + 32*kg
    __shared__ float sVelP[4][32];

    if (blockIdx.x >= PGB) {
        // ---- scatter branch: sorted edata {row, col, rad_bits, orig_e} ----
        int e = (blockIdx.x - PGB) * 256 + threadIdx.x;
        if (e < EE) {
            int r = row[e];
            u32 p = use_ext ? (cursor[r] + rank[e]) : atomicAdd(&cursor[r], 1u);
            float cx = cdiff[(size_t)e * 3 + 0];
            float cy = cdiff[(size_t)e * 3 + 1];
            float cz = cdiff[(size_t)e * 3 + 2];
            float rad = cx * cx + cy * cy + cz * cz;
            uint4 ed;
            ed.x = (u32)r;
            ed.y = (u32)col[e];
            ed.z = __float_as_uint(rad);
            ed.w = (u32)e;
            *(uint4*)(edata + (size_t)p * 4) = ed;
        }
        return;
    }

    const int tid = threadIdx.x;
    const int nblk = blockIdx.x * 32;
    const int w = tid >> 6;
    const int lane = tid & 63;
    const int m15 = lane & 15, q = lane >> 4;
    const int n0 = w * 32 + 2 * m15, n1 = n0 + 1;
    const int ard = (m15 + 32 * q) * 8;
    const float b0 = be1[n0], b1 = be1[n1];

    {
        int r = tid & 31, j = tid >> 5;          // j = 0..7
        int n = nblk + r; if (n > NN - 1) n = NN - 1;
        #pragma unroll
        for (int i = 0; i < 2; ++i) {
            int kg = j * 2 + i;                  // 0..15
            const float* src = h + (size_t)n * 128 + kg * 8;
            float4 a = *(const float4*)(src);
            float4 b = *(const float4*)(src + 4);
            uint4 v = make_uint4(pkr(a.x, a.y), pkr(a.z, a.w),
                                 pkr(b.x, b.y), pkr(b.z, b.w));
            *(uint4*)&sX[(r + 32 * kg) * 8] = v;
            if (use_ext)
                *(uint4*)(hbf + (size_t)n * 128 + kg * 8) = v;
        }
    }
    __syncthreads();

    f32x4 acc[2][2];

    // P1: We1 k-rows 0..127 (chunks c=0..3), bias be1 folded
    #pragma unroll
    for (int mt = 0; mt < 2; ++mt)
        #pragma unroll
        for (int r = 0; r < 4; ++r) { acc[mt][0][r] = b0; acc[mt][1][r] = b1; }
    #pragma unroll
    for (int c = 0; c < 4; ++c) {
        short8 bf0 = *(const short8*)(We1bf + (c * 8 + w * 2 + 0) * 512 + lane * 8);
        short8 bf1 = *(const short8*)(We1bf + (c * 8 + w * 2 + 1) * 512 + lane * 8);
        #pragma unroll
        for (int mt = 0; mt < 2; ++mt) {
            short8 af = *(const short8*)(sX + ard + c * 1024 + mt * 128);
            acc[mt][0] = __builtin_amdgcn_mfma_f32_16x16x32_bf16(af, bf0, acc[mt][0], 0, 0, 0);
            acc[mt][1] = __builtin_amdgcn_mfma_f32_16x16x32_bf16(af, bf1, acc[mt][1], 0, 0, 0);
        }
    }
    #pragma unroll
    for (int mt = 0; mt < 2; ++mt)
        #pragma unroll
        for (int r = 0; r < 4; ++r) {
            int n = nblk + mt * 16 + q * 4 + r;
            if (n < NN)
                *(u32*)(P1bf + (size_t)n * 128 + n0) = pkr(acc[mt][0][r], acc[mt][1][r]);
        }

    // P2: We1 k-rows 128..255 (chunks c=4..7), no bias; same A tile
    #pragma unroll
    for (int mt = 0; mt < 2; ++mt)
        #pragma unroll
        for (int r = 0; r < 4; ++r) { acc[mt][0][r] = 0.0f; acc[mt][1][r] = 0.0f; }
    #pragma unroll
    for (int c = 4; c < 8; ++c) {
        short8 bf0 = *(const short8*)(We1bf + (c * 8 + w * 2 + 0) * 512 + lane * 8);
        short8 bf1 = *(const short8*)(We1bf + (c * 8 + w * 2 + 1) * 512 + lane * 8);
        #pragma unroll
        for (int mt = 0; mt < 2; ++mt) {
            short8 af = *(const short8*)(sX + ard + (c - 4) * 1024 + mt * 128);
            acc[mt][0] = __builtin_amdgcn_mfma_f32_16x16x32_bf16(af, bf0, acc[mt][0], 0, 0, 0);
            acc[mt][1] = __builtin_amdgcn_mfma_f32_16x16x32_bf16(af, bf1, acc[mt][1], 0, 0, 0);
        }
    }
    #pragma unroll
    for (int mt = 0; mt < 2; ++mt)
        #pragma unroll
        for (int r = 0; r < 4; ++r) {
            int n = nblk + mt * 16 + q * 4 + r;
            if (n < NN)
                *(u32*)(P2bf + (size_t)n * 128 + n0) = pkr(acc[mt][0][r], acc[mt][1][r]);
        }

    // ---- vel head: vel = silu(h@Wv1+bv1)@Wv2 + bv2 (reuses staged h) ----
    {
        const float bva = bv1[n0], bvb = bv1[n1];
        const float wv2a = Wv2[n0], wv2b = Wv2[n1];
        #pragma unroll
        for (int mt = 0; mt < 2; ++mt)
            #pragma unroll
            for (int r = 0; r < 4; ++r) { acc[mt][0][r] = bva; acc[mt][1][r] = bvb; }
        #pragma unroll
        for (int c = 0; c < 4; ++c) {
            short8 bf0 = *(const short8*)(Wv1bf + (c * 8 + w * 2 + 0) * 512 + lane * 8);
            short8 bf1 = *(const short8*)(Wv1bf + (c * 8 + w * 2 + 1) * 512 + lane * 8);
            #pragma unroll
            for (int mt = 0; mt < 2; ++mt) {
                short8 af = *(const short8*)(sX + ard + c * 1024 + mt * 128);
                acc[mt][0] = __builtin_amdgcn_mfma_f32_16x16x32_bf16(af, bf0, acc[mt][0], 0, 0, 0);
                acc[mt][1] = __builtin_amdgcn_mfma_f32_16x16x32_bf16(af, bf1, acc[mt][1], 0, 0, 0);
            }
        }
        #pragma unroll
        for (int mt = 0; mt < 2; ++mt)
            #pragma unroll
            for (int r = 0; r < 4; ++r) {
                float pv = fmaf(siluf(acc[mt][0][r]), wv2a, siluf(acc[mt][1][r]) * wv2b);
                pv += __shfl_xor(pv, 1);
                pv += __shfl_xor(pv, 2);
                pv += __shfl_xor(pv, 4);
                pv += __shfl_xor(pv, 8);
                if (m15 == 0) sVelP[w][mt * 16 + q * 4 + r] = pv;
            }
        __syncthreads();
        if (tid < 32) {
            int n = nblk + tid;
            if (n < NN)
                vel[n] = bv2[0] + sVelP[0][tid] + sVelP[1][tid] + sVelP[2][tid] + sVelP[3][tid];
        }
    }
}

// ---- edge kernel: R13-proven body + XCD-aware bijective block swizzle ----
__global__ __launch_bounds__(256, 8) void edge_kernel(
    const u16* __restrict__ P1bf, const u16* __restrict__ P2bf,
    const float* __restrict__ cdiff,
    const u32* __restrict__ edata,
    const float* __restrict__ We1,      // only row 256 (radial weights) used
    const float* __restrict__ be2, const float* __restrict__ bc1,
    const float* __restrict__ Wc2,
    const u16* __restrict__ We2bf, const u16* __restrict__ Wc1bf,
    u16* __restrict__ aggbf, float* __restrict__ fsum)
{
    __shared__ u16 sT[8192];        // 16KB swizzled A-fragment buffer (t1, then m)
    __shared__ int sRow[64];
    __shared__ int sEg[64];
    __shared__ int sRid[64];        // run-head index per edge (sorted rows)
    __shared__ float sCoefP[4][64];
    __shared__ float sF[192];       // per-run force accumulators [rid*3+ax]

    const int tid = threadIdx.x;
    // bijective XCD swizzle (nwg = EE/64 = 12500, 8 XCDs)
    const int xcd = blockIdx.x & 7, off = blockIdx.x >> 3;
    const int qq = 12500 >> 3, rr = 12500 & 7;      // 1562, 4
    const int lb = (xcd < rr ? xcd * (qq + 1) : rr * (qq + 1) + (xcd - rr) * qq) + off;
    const int e0 = lb * 64;
    const int w = tid >> 6;
    const int lane = tid & 63;
    const int m15 = lane & 15, q = lane >> 4;
    const int n0 = w * 32 + 2 * m15, n1 = n0 + 1;
    const int lsw = (lane ^ q) * 8;
    const int a_ = m15 >> 2;
    const int sbase = (a_ << 7) + (q << 5) + ((m15 & 3) << 1);
    const int o0 = (0 ^ a_) << 3, o1 = (1 ^ a_) << 3, o2 = (2 ^ a_) << 3, o3 = (3 ^ a_) << 3;

    const float b2a = be2[n0], b2b = be2[n1];
    const float b3a = bc1[n0], b3b = bc1[n1];
    const float wc2a = Wc2[n0], wc2b = Wc2[n1];

    // t1 = silu(P1[row] + P2[col] + rad*We1[256]) -> swizzled sT
    {
        int e = tid & 63, seg = tid >> 6;
        uint4 ed = *(const uint4*)(edata + (size_t)(e0 + e) * 4);
        int nr = (int)ed.x, nc = (int)ed.y;
        float rad = __uint_as_float(ed.z);
        if (seg == 0) { sRow[e] = nr; sEg[e] = (int)ed.w; }
        const u16* p1 = P1bf + (size_t)nr * 128 + seg * 32;
        const u16* p2 = P2bf + (size_t)nc * 128 + seg * 32;
        const float* wr = We1 + 256 * 128 + seg * 32;
        u16* tb = sT + (((seg * 4 + (e >> 4)) << 9) + (((e >> 2) & 3) << 5));
        const int rl = e & 3;
        #pragma unroll 2
        for (int g = 0; g < 4; ++g) {
            short8 x1 = *(const short8*)(p1 + g * 8);
            short8 x2 = *(const short8*)(p2 + g * 8);
            float4 wa = *(const float4*)(wr + g * 8);
            float4 wb = *(const float4*)(wr + g * 8 + 4);
            float v[8];
            #pragma unroll
            for (int t = 0; t < 4; ++t) {
                v[t]     = siluf(bf2f(x1[t])     + bf2f(x2[t])     + rad * ((const float*)&wa)[t]);
                v[t + 4] = siluf(bf2f(x1[t + 4]) + bf2f(x2[t + 4]) + rad * ((const float*)&wb)[t]);
            }
            uint4 dd = make_uint4(pkr(v[0], v[1]), pkr(v[2], v[3]),
                                  pkr(v[4], v[5]), pkr(v[6], v[7]));
            *(uint4*)(tb + ((g << 7) + ((rl ^ g) << 3))) = dd;
        }
    }
    __syncthreads();   // B1: t1 + sRow ready

    // run-head ids via 6-step max-scan (wave 0); zero force accumulators
    if (tid < 64) {
        int e = tid;
        int head = (e == 0) || (sRow[e] != sRow[e - 1]);
        int v = head ? e : 0;
        #pragma unroll
        for (int o = 1; o < 64; o <<= 1) {
            int y = __shfl_up(v, o);
            if (e >= o && y > v) v = y;
        }
        sRid[e] = v;
        sF[e * 3 + 0] = 0.f; sF[e * 3 + 1] = 0.f; sF[e * 3 + 2] = 0.f;
    }

    f32x4 acc[4][2];
    u32 d[4][4];

    // ---- GEMM2: m = silu(t1 @ We2 + be2), K=128 ----
    #pragma unroll
    for (int mt = 0; mt < 4; ++mt)
        #pragma unroll
        for (int r = 0; r < 4; ++r) { acc[mt][0][r] = b2a; acc[mt][1][r] = b2b; }
    #pragma unroll
    for (int c = 0; c < 4; ++c) {
        short8 bf0 = *(const short8*)(We2bf + (c * 8 + w * 2 + 0) * 512 + lane * 8);
        short8 bf1 = *(const short8*)(We2bf + (c * 8 + w * 2 + 1) * 512 + lane * 8);
        #pragma unroll
        for (int mt = 0; mt < 4; ++mt) {
            short8 af = *(const short8*)(sT + (c * 4 + mt) * 512 + lsw);
            acc[mt][0] = __builtin_amdgcn_mfma_f32_16x16x32_bf16(af, bf0, acc[mt][0], 0, 0, 0);
            acc[mt][1] = __builtin_amdgcn_mfma_f32_16x16x32_bf16(af, bf1, acc[mt][1], 0, 0, 0);
        }
    }
    #pragma unroll
    for (int mt = 0; mt < 4; ++mt)
        #pragma unroll
        for (int r = 0; r < 4; ++r)
            d[mt][r] = pkr(siluf(acc[mt][0][r]), siluf(acc[mt][1][r]));
    __syncthreads();   // B2: all sT reads done -> reuse for m
    #pragma unroll
    for (int mt = 0; mt < 4; ++mt) {
        u16* bp = sT + (w * 4 + mt) * 512 + sbase;
        *(u32*)(bp + o0) = d[mt][0];
        *(u32*)(bp + o1) = d[mt][1];
        *(u32*)(bp + o2) = d[mt][2];
        *(u32*)(bp + o3) = d[mt][3];
    }
    __syncthreads();   // B3: m ready

    // ---- GEMM3: u = silu(m @ Wc1 + bc1); coef fused via shfl reduce ----
    #pragma unroll
    for (int mt = 0; mt < 4; ++mt)
        #pragma unroll
        for (int r = 0; r < 4; ++r) { acc[mt][0][r] = b3a; acc[mt][1][r] = b3b; }
    #pragma unroll
    for (int c = 0; c < 4; ++c) {
        short8 bf0 = *(const short8*)(Wc1bf + (c * 8 + w * 2 + 0) * 512 + lane * 8);
        short8 bf1 = *(const short8*)(Wc1bf + (c * 8 + w * 2 + 1) * 512 + lane * 8);
        #pragma unroll
        for (int mt = 0; mt < 4; ++mt) {
            short8 af = *(const short8*)(sT + (c * 4 + mt) * 512 + lsw);
            acc[mt][0] = __builtin_amdgcn_mfma_f32_16x16x32_bf16(af, bf0, acc[mt][0], 0, 0, 0);
            acc[mt][1] = __builtin_amdgcn_mfma_f32_16x16x32_bf16(af, bf1, acc[mt][1], 0, 0, 0);
        }
    }
    #pragma unroll
    for (int mt = 0; mt < 4; ++mt)
        #pragma unroll
        for (int r = 0; r < 4; ++r) {
            float pv = fmaf(siluf(acc[mt][0][r]), wc2a, siluf(acc[mt][1][r]) * wc2b);
            pv += __shfl_xor(pv, 1);
            pv += __shfl_xor(pv, 2);
            pv += __shfl_xor(pv, 4);
            pv += __shfl_xor(pv, 8);
            if (m15 == 0) sCoefP[w][mt * 16 + q * 4 + r] = pv;
        }

    // ---- agg: run-length aggregate m over sorted rows, 1 pk-atomic per run ----
    {
        const int P = tid & 63, C = 2 * P, g = tid >> 6;
        const int xorb = (C >> 3) & 3;
        const int base = ((((C >> 5) * 4 + g) << 9)) + (((C >> 3) & 3) << 7) + (C & 7);
        float s0 = 0.f, s1 = 0.f;
        int prow = sRow[g * 16];
        #pragma unroll
        for (int i = 0; i < 16; ++i) {
            u32 v = *(const u32*)(sT + base + (((i >> 2) & 3) << 5) + (((i & 3) ^ xorb) << 3));
            int r = sRow[g * 16 + i];
            if (r != prow) {
                atomic_pk_add_bf16(aggbf + (size_t)prow * 128 + C, pkr(s0, s1));
                s0 = 0.f; s1 = 0.f; prow = r;
            }
            s0 += bf2f((short)(v & 0xffffu));
            s1 += bf2f((short)(v >> 16));
        }
        atomic_pk_add_bf16(aggbf + (size_t)prow * 128 + C, pkr(s0, s1));
    }
    __syncthreads();   // B4: coef partials + sRid + sF ready

    // force: per-edge clamped tr -> LDS run accumulators -> 1 atomic/(run,ax)
    if (tid < 192) {
        int e = tid / 3, ax = tid - e * 3;
        float coef = sCoefP[0][e] + sCoefP[1][e] + sCoefP[2][e] + sCoefP[3][e];
        float tr = cdiff[(size_t)sEg[e] * 3 + ax] * coef;
        tr = fminf(fmaxf(tr, -100.f), 100.f);
        atomicAdd(&sF[sRid[e] * 3 + ax], tr);
    }
    __syncthreads();   // B5: LDS force sums complete
    if (tid < 192) {
        int e = tid / 3, ax = tid - e * 3;
        if (e == 0 || sRow[e] != sRow[e - 1])
            atomicAdd(&fsum[(size_t)sRow[e] * 3 + ax], sF[e * 3 + ax]);
    }
}

// ---- node kernel: 32 nodes/block (1563 blocks), 4 waves; no vel head ----
__global__ __launch_bounds__(256, 4) void node_kernel(
    const float* __restrict__ h, const u16* __restrict__ hbf, u32 use_ext,
    const float* __restrict__ bn1, const float* __restrict__ bn2,
    const u16* __restrict__ Wn1bf, const u16* __restrict__ Wn2bf,
    const u16* __restrict__ aggbf, const float* __restrict__ fsum,
    const u32* __restrict__ bins, float* __restrict__ out)
{
    __shared__ u16 sX[8192];           // 16KB: 32 nodes x 256 k, slot = r + 32*kg
    __shared__ float sBn1[128], sBn2[128];
    u16* sT = sX + 4096;               // aliases agg half (k=128..255) after GEMM1

    const int tid = threadIdx.x;
    const int nblk = blockIdx.x * 32;
    const int w = tid >> 6;
    const int lane = tid & 63;
    const int m15 = lane & 15, q = lane >> 4;
    const int n0 = w * 32 + 2 * m15, n1 = n0 + 1;
    const int lsw = (lane ^ q) * 8;
    const int a_ = m15 >> 2;
    const int sbase = (a_ << 7) + (q << 5) + ((m15 & 3) << 1);
    const int o0 = (0 ^ a_) << 3, o1 = (1 ^ a_) << 3, o2 = (2 ^ a_) << 3, o3 = (3 ^ a_) << 3;
    const int ard = (m15 + 32 * q) * 8;

    if (tid < 96) {
        int r = tid / 3, ax = tid - r * 3;
        int n = nblk + r;
        if (n < NN)
            out[NN + (size_t)n * 3 + ax] = fsum[(size_t)n * 3 + ax] * __builtin_amdgcn_rcpf(fmaxf((float)bins[n], 1.0f));
    }
    if (tid < 128) { sBn1[tid] = bn1[tid]; sBn2[tid] = bn2[tid]; }

    {
        int r = tid & 31, j = tid >> 5;            // j = 0..7
        int n = nblk + r; if (n > NN - 1) n = NN - 1;
        if (j < 4) {
            if (use_ext) {
                #pragma unroll
                for (int i = 0; i < 4; ++i) {
                    int kg = j * 4 + i;            // 0..15  (h, k=0..127)
                    *(uint4*)&sX[(r + 32 * kg) * 8] =
                        *(const uint4*)(hbf + (size_t)n * 128 + kg * 8);
                }
            } else {
                #pragma unroll
                for (int i = 0; i < 4; ++i) {
                    int kg = j * 4 + i;
                    const float* src = h + (size_t)n * 128 + kg * 8;
                    float4 a = *(const float4*)(src);
                    float4 b = *(const float4*)(src + 4);
                    *(uint4*)&sX[(r + 32 * kg) * 8] = make_uint4(pkr(a.x, a.y), pkr(a.z, a.w),
                                                                 pkr(b.x, b.y), pkr(b.z, b.w));
                }
            }
        } else {
            #pragma unroll
            for (int i = 0; i < 4; ++i) {
                int kg = j * 4 + i;                // 16..31 (agg, k=128..255)
                *(uint4*)&sX[(r + 32 * kg) * 8] =
                    *(const uint4*)(aggbf + (size_t)n * 128 + (kg - 16) * 8);
            }
        }
    }
    __syncthreads();

    f32x4 acc[2][2];

    {
        float b0 = sBn1[n0], b1 = sBn1[n1];
        #pragma unroll
        for (int mt = 0; mt < 2; ++mt)
            #pragma unroll
            for (int r = 0; r < 4; ++r) { acc[mt][0][r] = b0; acc[mt][1][r] = b1; }
    }
    #pragma unroll
    for (int c = 0; c < 8; ++c) {
        short8 bf0 = *(const short8*)(Wn1bf + (c * 8 + w * 2 + 0) * 512 + lane * 8);
        short8 bf1 = *(const short8*)(Wn1bf + (c * 8 + w * 2 + 1) * 512 + lane * 8);
        #pragma unroll
        for (int mt = 0; mt < 2; ++mt) {
            short8 af = *(const short8*)(sX + ard + c * 1024 + mt * 128);
            acc[mt][0] = __builtin_amdgcn_mfma_f32_16x16x32_bf16(af, bf0, acc[mt][0], 0, 0, 0);
            acc[mt][1] = __builtin_amdgcn_mfma_f32_16x16x32_bf16(af, bf1, acc[mt][1], 0, 0, 0);
        }
    }
    u32 dn[2][4];
    #pragma unroll
    for (int mt = 0; mt < 2; ++mt)
        #pragma unroll
        for (int r = 0; r < 4; ++r)
            dn[mt][r] = pkr(siluf(acc[mt][0][r]), siluf(acc[mt][1][r]));
    __syncthreads();
    #pragma unroll
    for (int mt = 0; mt < 2; ++mt) {
        u16* bp = sT + (w * 2 + mt) * 512 + sbase;
        *(u32*)(bp + o0) = dn[mt][0];
        *(u32*)(bp + o1) = dn[mt][1];
        *(u32*)(bp + o2) = dn[mt][2];
        *(u32*)(bp + o3) = dn[mt][3];
    }
    __syncthreads();

    {
        float b0 = sBn2[n0], b1 = sBn2[n1];
        #pragma unroll
        for (int mt = 0; mt < 2; ++mt)
            #pragma unroll
            for (int r = 0; r < 4; ++r) { acc[mt][0][r] = b0; acc[mt][1][r] = b1; }
    }
    #pragma unroll
    for (int c = 0; c < 4; ++c) {
        short8 bf0 = *(const short8*)(Wn2bf + (c * 8 + w * 2 + 0) * 512 + lane * 8);
        short8 bf1 = *(const short8*)(Wn2bf + (c * 8 + w * 2 + 1) * 512 + lane * 8);
        #pragma unroll
        for (int mt = 0; mt < 2; ++mt) {
            short8 af = *(const short8*)(sT + (c * 2 + mt) * 512 + lsw);
            acc[mt][0] = __builtin_amdgcn_mfma_f32_16x16x32_bf16(af, bf0, acc[mt][0], 0, 0, 0);
            acc[mt][1] = __builtin_amdgcn_mfma_f32_16x16x32_bf16(af, bf1, acc[mt][1], 0, 0, 0);
        }
    }
    #pragma unroll
    for (int mt = 0; mt < 2; ++mt)
        #pragma unroll
        for (int r = 0; r < 4; ++r) {
            int n = nblk + mt * 16 + q * 4 + r;
            if (n < NN) {
                f32x2 v; v.x = acc[mt][0][r]; v.y = acc[mt][1][r];
                *(f32x2*)(out + (size_t)4 * NN + (size_t)n * 128 + n0) = v;
            }
        }
}

extern "C" void kernel_launch(void* const* d_in, const int* in_sizes, int n_in,
                              void* d_out, int out_size, void* d_ws, size_t ws_size,
                              hipStream_t stream) {
    const float* h     = (const float*)d_in[0];
    const float* cdiff = (const float*)d_in[1];
    const int* row     = (const int*)d_in[2];
    const int* col     = (const int*)d_in[3];
    const float* We1 = (const float*)d_in[4];
    const float* be1 = (const float*)d_in[5];
    const float* We2 = (const float*)d_in[6];
    const float* be2 = (const float*)d_in[7];
    const float* Wn1 = (const float*)d_in[8];
    const float* bn1 = (const float*)d_in[9];
    const float* Wn2 = (const float*)d_in[10];
    const float* bn2 = (const float*)d_in[11];
    const float* Wc1 = (const float*)d_in[12];
    const float* bc1 = (const float*)d_in[13];
    const float* Wc2 = (const float*)d_in[14];
    const float* Wv1 = (const float*)d_in[15];
    const float* bv1 = (const float*)d_in[16];
    const float* Wv2 = (const float*)d_in[17];
    const float* bv2 = (const float*)d_in[18];

    // base workspace (~26.7MB, verified layout):
    u16* aggbf  = (u16*)d_ws;                           // [NN*128] bf16
    float* fsum = (float*)(aggbf + (size_t)NN * 128);   // [NN*3]
    u32* bins   = (u32*)(fsum + (size_t)NN * 3);        // [NN]
    u16* We1bf = (u16*)(bins + NN);                     // [32768]
    u16* We2bf = We1bf + 32768;                         // [16384]
    u16* Wc1bf = We2bf + 16384;                         // [16384]
    u16* Wn1bf = Wc1bf + 16384;                         // [32768]
    u16* Wn2bf = Wn1bf + 32768;                         // [16384]
    u16* Wv1bf = Wn2bf + 16384;                         // [16384]
    u16* P1bf  = Wv1bf + 16384;                         // [NN*128] bf16
    float* out = (float*)d_out;

    // ws extensions: hbf + rank (39.7MB total; guarded)
    const size_t base_bytes = (size_t)26662144;
    u16* hbf  = (u16*)((char*)d_ws + base_bytes);                     // [NN*128]
    u32* rank = (u32*)((char*)d_ws + base_bytes + (size_t)NN * 256);  // [EE]
    u32 use_ext = (ws_size >= base_bytes + (size_t)NN * 256 + (size_t)EE * 4) ? 1u : 0u;

    // d_out: vel [0,NN) written by pgemm; force region [NN,4NN) hosts sort
    // scratch (cursor+part, 201KB of 600KB) until node overwrites it last.
    u32* cursor = (u32*)(out + NN);                     // [NN]
    u32* part   = cursor + NN;                          // [196]
    // h_out region (25.6MB): P2 (12.8) + edata (12.8) — consumed by edge
    u16* P2bf   = (u16*)(out + (size_t)4 * NN);         // [NN*128]
    u32* edata  = (u32*)(P2bf + (size_t)NN * 128);      // [EE*4] uint4/edge

    // bins only (200KB): aggbf+fsum zeroing is fused into prephist (same-launch
    // hist atomics forbid fusing bins zeroing — no inter-block ordering).
    hipMemsetAsync(bins, 0, (size_t)NN * 4, stream);

    const int NSC = (NN + 255) / 256;                   // 196 scan blocks

    prephist_kernel<<<512 + HB + ZB, 256, 0, stream>>>(
        We1, We2, Wc1, Wn1, Wn2, Wv1,
        We1bf, We2bf, Wc1bf, Wn1bf, Wn2bf, Wv1bf,
        row, bins, rank, use_ext, (uint4*)d_ws);
    scan1_kernel<<<NSC, 256, 0, stream>>>(bins, part);
    scan3_kernel<<<NSC, 256, 0, stream>>>(bins, part, cursor, NSC);
    pgemm_scatter_kernel<<<PGB + HB, 256, 0, stream>>>(
        h, be1, bv1, Wv2, bv2,
        We1bf, Wv1bf, P1bf, P2bf,
        hbf, use_ext, out,
        row, col, cdiff, cursor, rank, edata);
    edge_kernel<<<EE / 64, 256, 0, stream>>>(P1bf, P2bf, cdiff, edata,
                                             We1, be2, bc1, Wc2,
                                             We2bf, Wc1bf,
                                             aggbf, fsum);
    node_kernel<<<(NN + 31) / 32, 256, 0, stream>>>(h, hbf, use_ext,
                                                    bn1, bn2,
                                                    Wn1bf, Wn2bf,
                                                    aggbf, fsum, bins, out);
}